// Round 7
// baseline (917.630 us; speedup 1.0000x reference)
//
#include <hip/hip_runtime.h>

// B=8, N=HW=4096, D=512, I=256, DO=512
// ws (ushort offsets):
//   featT  @0        [b][n=4096][c=512] bf16 (k0a->k1); overlaid by out1 (k3->k4)
//   featV  @16777216 [b][mt=64][c=512][m=64] bf16 (k0a->k3)
//   phi_n  @33554432 [b][n][i=256] bf16 normalized (k1->k3)
//   theta_n@41943040 same (k1->k3)
//   wb_phi @50331648 [i=256][c=512] bf16 (k0b->k1)
//   wb_th  @50462720
//   weightT@50593792 [d=512][c=512] bf16 (k0c->k4)
// end 50855936 ushorts = 101.7 MB (<= proven 134 MB)

typedef short s8v __attribute__((ext_vector_type(8)));
typedef float f4v __attribute__((ext_vector_type(4)));

__device__ inline ushort f2bf(float x) {
  union { float f; unsigned u; } v; v.f = x;
  unsigned u = v.u + 0x7fff + ((v.u >> 16) & 1);
  return (ushort)(u >> 16);
}

// 16B global -> LDS direct DMA (no VGPR round-trip). gptr per-lane, lptr
// wave-uniform; HW writes lptr + lane*16. (Verified in R6 run.)
__device__ inline void gload16(const ushort* g, ushort* l) {
  __builtin_amdgcn_global_load_lds(
      (const __attribute__((address_space(1))) unsigned int*)g,
      (__attribute__((address_space(3))) unsigned int*)l, 16, 0, 0);
}

// ---------- k0a: feat fp32 [b][c][m] -> featV blocked bf16 + featT bf16 ----
// grid 4096 = 8b x 8cb x 64mt, block 256
__global__ __launch_bounds__(256) void k0a(const float* __restrict__ feat,
                                           ushort* __restrict__ featT,
                                           ushort* __restrict__ featV) {
  int bid = blockIdx.x;
  int b = bid >> 9, cb = (bid >> 6) & 7, mt = bid & 63;
  int t = threadIdx.x;
  __shared__ ushort tile[64][72];

#pragma unroll
  for (int p = 0; p < 4; p++) {
    int ci = p * 16 + (t >> 4);
    int mi = (t & 15) * 4;
    float4 v = *(const float4*)&feat[((size_t)(b * 512 + cb * 64 + ci)) * 4096 + mt * 64 + mi];
    ushort4 u; u.x = f2bf(v.x); u.y = f2bf(v.y); u.z = f2bf(v.z); u.w = f2bf(v.w);
    *(ushort4*)&featV[((size_t)(b * 64 + mt) * 512 + cb * 64 + ci) * 64 + mi] = u;
    tile[ci][mi] = u.x; tile[ci][mi + 1] = u.y; tile[ci][mi + 2] = u.z; tile[ci][mi + 3] = u.w;
  }
  __syncthreads();
  int m = t >> 2, cs = (t & 3) * 16;
  ushort tmp[16];
#pragma unroll
  for (int j = 0; j < 16; j++) tmp[j] = tile[cs + j][m];
  ushort* dst = &featT[((size_t)(b * 4096 + mt * 64 + m)) * 512 + cb * 64 + cs];
  *(s8v*)dst = *(s8v*)&tmp[0];
  *(s8v*)(dst + 8) = *(s8v*)&tmp[8];
}

// ---------- k0b: cast phi_w / theta_w -> bf16 ------------------------------
__global__ __launch_bounds__(256) void k0b(const float* __restrict__ pw,
                                           const float* __restrict__ tw,
                                           ushort* __restrict__ wbp,
                                           ushort* __restrict__ wbt) {
  int bid = blockIdx.x;
  const float* src = (bid < 128) ? pw : tw;
  ushort* dst = (bid < 128) ? wbp : wbt;
  int idx = ((bid & 127) * 256 + threadIdx.x) * 4;
  float4 v = *(const float4*)&src[idx];
  ushort4 u; u.x = f2bf(v.x); u.y = f2bf(v.y); u.z = f2bf(v.z); u.w = f2bf(v.w);
  *(ushort4*)&dst[idx] = u;
}

// ---------- k0c: weight fp32 [c][d] -> weightT bf16 [d][c] -----------------
// grid 64 = 8cb x 8db
__global__ __launch_bounds__(256) void k0c(const float* __restrict__ w,
                                           ushort* __restrict__ wT) {
  int bid = blockIdx.x;
  int cb = bid >> 3, db = bid & 7;
  int t = threadIdx.x;
  __shared__ ushort tile[64][72];
#pragma unroll
  for (int p = 0; p < 4; p++) {
    int ci = p * 16 + (t >> 4);
    int di = (t & 15) * 4;
    float4 v = *(const float4*)&w[(size_t)(cb * 64 + ci) * 512 + db * 64 + di];
    tile[ci][di] = f2bf(v.x); tile[ci][di + 1] = f2bf(v.y);
    tile[ci][di + 2] = f2bf(v.z); tile[ci][di + 3] = f2bf(v.w);
  }
  __syncthreads();
  int d = t >> 2, cs = (t & 3) * 16;
  ushort tmp[16];
#pragma unroll
  for (int j = 0; j < 16; j++) tmp[j] = tile[cs + j][d];
  ushort* dst = &wT[(size_t)(db * 64 + d) * 512 + cb * 64 + cs];
  *(s8v*)dst = *(s8v*)&tmp[0];
  *(s8v*)(dst + 8) = *(s8v*)&tmp[8];
}

// ---------- k1: phi/theta MFMA GEMM + fused L2-normalize -> bf16 -----------
// grid 512 = 8b x 32nt x 2half, block 512 (8 waves x 16 n-rows, all 256 i)
__global__ __launch_bounds__(512) void k1_gemm(
    const ushort* __restrict__ featT, const ushort* __restrict__ wbp,
    const ushort* __restrict__ wbt, ushort* __restrict__ phi_n,
    ushort* __restrict__ theta_n) {
  int bid = blockIdx.x;
  int b = bid & 7;
  int rest = bid >> 3;
  int half = rest & 1;
  int nt = rest >> 1;
  const ushort* wb = half ? wbt : wbp;
  ushort* dst = half ? theta_n : phi_n;
  int t = threadIdx.x;
  int lane = t & 63, w = t >> 6;
  int col = lane & 15, quad = lane >> 4;
  int n0 = nt * 128;

  const ushort* abase =
      featT + ((size_t)(b * 4096 + n0 + w * 16 + col)) * 512 + quad * 8;

  f4v acc[16];
#pragma unroll
  for (int i = 0; i < 16; i++) acc[i] = (f4v){0.f, 0.f, 0.f, 0.f};

#pragma unroll 2
  for (int kc = 0; kc < 16; kc++) {
    s8v a = *(const s8v*)(abase + kc * 32);
#pragma unroll
    for (int it = 0; it < 16; it++) {
      s8v bf = *(const s8v*)(wb + (size_t)(it * 16 + col) * 512 + kc * 32 + quad * 8);
      acc[it] = __builtin_amdgcn_mfma_f32_16x16x32_bf16(a, bf, acc[it], 0, 0, 0);
    }
  }
  // fused normalize: lane holds rows n = w*16 + quad*4 + reg, cols i = it*16+col
  float rinv[4];
#pragma unroll
  for (int reg = 0; reg < 4; reg++) {
    float ss = 0.f;
#pragma unroll
    for (int it = 0; it < 16; it++) ss += acc[it][reg] * acc[it][reg];
    ss += __shfl_xor(ss, 1); ss += __shfl_xor(ss, 2);
    ss += __shfl_xor(ss, 4); ss += __shfl_xor(ss, 8);
    rinv[reg] = rsqrtf(ss);
  }
#pragma unroll
  for (int it = 0; it < 16; it++) {
#pragma unroll
    for (int reg = 0; reg < 4; reg++) {
      dst[((size_t)(b * 4096 + n0 + w * 16 + quad * 4 + reg)) * 256 + it * 16 + col] =
          f2bf(acc[it][reg] * rinv[reg]);
    }
  }
}

// ---------- k3: MFMA flash attention v8 — two independent 4-wave blocks ----
// grid 1024 = 8b(LSB) x 128qt(32 rows), block 256 = 4 waves, 2 blocks/CU.
// Same 8 waves/CU and per-wave register shape as R1 (champion, no spill),
// but the two co-resident blocks have INDEPENDENT barriers: block A's PV
// overlaps block B's barrier drain. Per-wave: dual Q-set (qfA/qfB, 32 rows),
// mh4=w (16 m-cols), 16 QK MFMA; PV owns 128 c-cols (acc[16]), 32 PV MFMA.
// K staged via global_load_lds DMA (R6-verified pattern: linear dest +
// inverse-swizzled per-lane source), SINGLE K buffer, 2 barriers/iter
// (R4-verified protocol):
//   [Vload,QK,exp,Pwrite] b1 [K-DMA(mt+1), PV] b2 (b2 drains vmcnt).
// LDS 36.5KB/block -> 73KB/CU. launch_bounds(256,2) -> 256-reg tier.
__global__ __launch_bounds__(256, 2) void k3_attn(
    const ushort* __restrict__ phi_n, const ushort* __restrict__ theta_n,
    const ushort* __restrict__ featV, ushort* __restrict__ out1) {
  int bid = blockIdx.x;
  int b = bid & 7;
  int n0 = (bid >> 3) << 5;  // 32-row q-tile
  int t = threadIdx.x;
  int lane = t & 63, w = t >> 6;  // w = 0..3 = mh4
  int col = lane & 15, quad = lane >> 4;
  int l32 = lane & 31, h32 = lane >> 5;
  int cs = col & 7;

  __shared__ __align__(16) ushort ks[16384];  // [row*256 + pos*8]; pos p holds chunk p^(row&7)
  __shared__ __align__(16) ushort ps[2048];   // [n=32][64]: n*64 + (chunk^(n&7))*8
  __shared__ float dred[4 * 32];              // [mh4][n]

  // Q A-frags, two 16-row sets: rows n0 + set*16 + col, k = f*32 + quad*8
  s8v qfA[8], qfB[8];
  {
    const ushort* qa = phi_n + ((size_t)(b * 4096 + n0 + col)) * 256 + quad * 8;
#pragma unroll
    for (int f = 0; f < 8; f++) qfA[f] = *(const s8v*)(qa + f * 32);
    const ushort* qb = qa + 16 * 256;
#pragma unroll
    for (int f = 0; f < 8; f++) qfB[f] = *(const s8v*)(qb + f * 32);
  }

  const ushort* thb = theta_n + (size_t)b * 4096 * 256;
  const ushort* vbb = featV + (size_t)b * 64 * 512 * 64 + (size_t)(w * 128) * 64;

  f4v acc[16];
#pragma unroll
  for (int i = 0; i < 16; i++) acc[i] = (f4v){0.f, 0.f, 0.f, 0.f};
  float denp[8] = {0.f, 0.f, 0.f, 0.f, 0.f, 0.f, 0.f, 0.f};  // [set*4+r]

  // stage tile 0 via DMA: wave stages 16 rows (8 DMA x 2 rows)
#pragma unroll
  for (int u = 0; u < 8; u++) {
    int row0 = w * 16 + u * 2;  // wave-uniform
    int row = row0 + h32;       // per-lane
    gload16(thb + (size_t)row * 256 + ((l32 ^ (row & 7)) * 8), ks + row0 * 256);
  }
  __syncthreads();  // drains vmcnt -> tile 0 visible

#pragma unroll 1
  for (int mt = 0; mt < 64; mt++) {
    // V B-frags: wave's 128-c range, both 32-m halves (consumed after b1)
    s8v v0[8], v1[8];
    {
      const ushort* vb = vbb + (size_t)mt * 32768;
#pragma unroll
      for (int ct = 0; ct < 8; ct++) {
        const ushort* p = vb + (ct * 16 + col) * 64 + quad * 8;
        v0[ct] = *(const s8v*)p;
        v1[ct] = *(const s8v*)(p + 32);
      }
    }

    // QK: each K B-frag (16 m-cols w*16+col) feeds both Q row-sets
    f4v svA = (f4v){0.f, 0.f, 0.f, 0.f};
    f4v svB = (f4v){0.f, 0.f, 0.f, 0.f};
    {
      const ushort* kb = ks + (w * 16 + col) * 256;
      __builtin_amdgcn_s_setprio(1);
#pragma unroll
      for (int kk = 0; kk < 8; kk++) {
        int pos = ((kk * 4 + quad) ^ cs) * 8;
        s8v bf = *(const s8v*)(kb + pos);
        svA = __builtin_amdgcn_mfma_f32_16x16x32_bf16(qfA[kk], bf, svA, 0, 0, 0);
        svB = __builtin_amdgcn_mfma_f32_16x16x32_bf16(qfB[kk], bf, svB, 0, 0, 0);
      }
      __builtin_amdgcn_s_setprio(0);
    }

    float pA[4], pB[4];
#pragma unroll
    for (int r = 0; r < 4; r++) {
      pA[r] = __expf(svA[r]);
      pB[r] = __expf(svB[r]);
      denp[r] += pA[r];
      denp[4 + r] += pB[r];
    }

    // P -> LDS (swizzled): rows nA = quad*4+r (set A), nB = nA+16 (set B)
    {
      int j0 = w * 2 + (col >> 3);
#pragma unroll
      for (int r = 0; r < 4; r++) {
        int nA = quad * 4 + r;
        ps[nA * 64 + ((j0 ^ (nA & 7)) * 8) + cs] = f2bf(pA[r]);
        int nB = nA + 16;
        ps[nB * 64 + ((j0 ^ (nB & 7)) * 8) + cs] = f2bf(pB[r]);
      }
    }
    __syncthreads();  // b1: QK done reading ks; P visible

    // issue next K tile DMA into ks (single buffer; b2's vmcnt drain covers it)
    if (mt < 63) {
      int m1 = (mt + 1) << 6;
#pragma unroll
      for (int u = 0; u < 8; u++) {
        int row0 = w * 16 + u * 2;
        int row = row0 + h32;
        gload16(thb + (size_t)(m1 + row) * 256 + ((l32 ^ (row & 7)) * 8),
                ks + row0 * 256);
      }
    }

    // PV: A = P (2 rowsets of 16), B = v0/v1 (wave's 128-c range)
    __builtin_amdgcn_s_setprio(1);
#pragma unroll
    for (int rs = 0; rs < 2; rs++) {
      const ushort* pb = ps + (rs * 16 + col) * 64;
      s8v pf0 = *(const s8v*)(pb + ((quad ^ cs) * 8));
      s8v pf1 = *(const s8v*)(pb + (((quad + 4) ^ cs) * 8));
#pragma unroll
      for (int ct = 0; ct < 8; ct++) {
        acc[rs * 8 + ct] =
            __builtin_amdgcn_mfma_f32_16x16x32_bf16(pf0, v0[ct], acc[rs * 8 + ct], 0, 0, 0);
        acc[rs * 8 + ct] =
            __builtin_amdgcn_mfma_f32_16x16x32_bf16(pf1, v1[ct], acc[rs * 8 + ct], 0, 0, 0);
      }
    }
    __builtin_amdgcn_s_setprio(0);
    __syncthreads();  // b2: PV done reading ps; K DMA drained (vmcnt 0)
  }

  // denominator: reduce over 16-col group, then across the 4 mh4 waves
#pragma unroll
  for (int i = 0; i < 8; i++) {
    float d = denp[i];
    d += __shfl_xor(d, 1); d += __shfl_xor(d, 2);
    d += __shfl_xor(d, 4); d += __shfl_xor(d, 8);
    denp[i] = d;
  }
  if (col == 0) {
#pragma unroll
    for (int i = 0; i < 8; i++) {
      int n = (i >> 2) * 16 + quad * 4 + (i & 3);
      dred[w * 32 + n] = denp[i];
    }
  }
  __syncthreads();
  if (t < 32) dred[t] = 1.0f / (dred[t] + dred[32 + t] + dred[64 + t] + dred[96 + t]);
  __syncthreads();

  // store out1 bf16 [n][c]: D[n=rs*16+quad*4+reg][c=w*128+ct*16+col]
#pragma unroll
  for (int rs = 0; rs < 2; rs++) {
#pragma unroll
    for (int ct = 0; ct < 8; ct++) {
#pragma unroll
      for (int reg = 0; reg < 4; reg++) {
        int n = rs * 16 + quad * 4 + reg;
        out1[((size_t)(b * 4096 + n0 + n)) * 512 + w * 128 + ct * 16 + col] =
            f2bf(acc[rs * 8 + ct][reg] * dred[n]);
      }
    }
  }
}

// ---------- k4: out = relu(weightT_bf @ out1^T) stored [b][d][n] fp32 ------
// grid 512 = 8b x 4dt x 16nt, block 512 = 8 waves (dw=w&1 -> 64d, nw=w>>1 -> 64n)
__global__ __launch_bounds__(512) void k4_out(
    const ushort* __restrict__ out1, const ushort* __restrict__ wT,
    float* __restrict__ out) {
  int bid = blockIdx.x;
  int b = bid & 7;
  int rest = bid >> 3;
  int dt = rest & 3;
  int nt = rest >> 2;
  int t = threadIdx.x;
  int lane = t & 63, w = t >> 6;
  int col = lane & 15, quad = lane >> 4;
  int dw = w & 1, nw = w >> 1;
  int d0 = dt * 128 + dw * 64;
  int n0 = nt * 256 + nw * 64;

  f4v acc[16];
#pragma unroll
  for (int i = 0; i < 16; i++) acc[i] = (f4v){0.f, 0.f, 0.f, 0.f};

#pragma unroll 2
  for (int kc = 0; kc < 16; kc++) {
    s8v af[4], bf[4];
#pragma unroll
    for (int rs = 0; rs < 4; rs++)
      af[rs] = *(const s8v*)(wT + (size_t)(d0 + rs * 16 + col) * 512 + kc * 32 + quad * 8);
#pragma unroll
    for (int ct = 0; ct < 4; ct++)
      bf[ct] = *(const s8v*)(out1 + ((size_t)(b * 4096 + n0 + ct * 16 + col)) * 512 +
                             kc * 32 + quad * 8);
#pragma unroll
    for (int rs = 0; rs < 4; rs++)
#pragma unroll
      for (int ct = 0; ct < 4; ct++)
        acc[rs * 4 + ct] =
            __builtin_amdgcn_mfma_f32_16x16x32_bf16(af[rs], bf[ct], acc[rs * 4 + ct], 0, 0, 0);
  }
#pragma unroll
  for (int rs = 0; rs < 4; rs++) {
#pragma unroll
    for (int ct = 0; ct < 4; ct++) {
#pragma unroll
      for (int reg = 0; reg < 4; reg++) {
        int d = d0 + rs * 16 + quad * 4 + reg;
        int n = n0 + ct * 16 + col;
        out[((size_t)(b * 512 + d)) * 4096 + n] = fmaxf(acc[rs * 4 + ct][reg], 0.f);
      }
    }
  }
}

extern "C" void kernel_launch(void* const* d_in, const int* in_sizes, int n_in,
                              void* d_out, int out_size, void* d_ws, size_t ws_size,
                              hipStream_t stream) {
  const float* feat    = (const float*)d_in[0];
  const float* phi_w   = (const float*)d_in[1];
  const float* theta_w = (const float*)d_in[2];
  const float* weight  = (const float*)d_in[3];
  float* out = (float*)d_out;

  ushort* wsu = (ushort*)d_ws;
  ushort* featT   = wsu;                    // dead after k1 -> reused as out1
  ushort* featV   = wsu + 16777216;
  ushort* phi_n   = wsu + 33554432;
  ushort* theta_n = wsu + 41943040;
  ushort* wbp     = wsu + 50331648;
  ushort* wbt     = wsu + 50462720;
  ushort* weightT = wsu + 50593792;
  ushort* out1    = wsu;                    // overlays featT

  k0a<<<dim3(4096), dim3(256), 0, stream>>>(feat, featT, featV);
  k0b<<<dim3(256), dim3(256), 0, stream>>>(phi_w, theta_w, wbp, wbt);
  k0c<<<dim3(64), dim3(256), 0, stream>>>(weight, weightT);
  k1_gemm<<<dim3(512), dim3(512), 0, stream>>>(featT, wbp, wbt, phi_n, theta_n);
  k3_attn<<<dim3(1024), dim3(256), 0, stream>>>(phi_n, theta_n, featV, out1);
  k4_out<<<dim3(512), dim3(512), 0, stream>>>(out1, weightT, out);
}

// Round 8
// 540.263 us; speedup vs baseline: 1.6985x; 1.6985x over previous
//
#include <hip/hip_runtime.h>

// B=8, N=HW=4096, D=512, I=256, DO=512
// ws (ushort offsets):
//   featT  @0        [b][n=4096][c=512] bf16 (k0a->k1); overlaid by out1 (k3->k4)
//   featV  @16777216 [b][mt=64][c=512][m=64] bf16 (k0a->k3)
//   phi_n  @33554432 [b][n][i=256] bf16 normalized (k1->k3)
//   theta_n@41943040 same (k1->k3)
//   wb_phi @50331648 [i=256][c=512] bf16 (k0b->k1)
//   wb_th  @50462720
//   weightT@50593792 [d=512][c=512] bf16 (k0c->k4)
// end 50855936 ushorts = 101.7 MB (<= proven 134 MB)

typedef short s8v __attribute__((ext_vector_type(8)));
typedef float f4v __attribute__((ext_vector_type(4)));

__device__ inline ushort f2bf(float x) {
  union { float f; unsigned u; } v; v.f = x;
  unsigned u = v.u + 0x7fff + ((v.u >> 16) & 1);
  return (ushort)(u >> 16);
}

// ---------- k0a: feat fp32 [b][c][m] -> featV blocked bf16 + featT bf16 ----
// grid 4096 = 8b x 8cb x 64mt, block 256
__global__ __launch_bounds__(256) void k0a(const float* __restrict__ feat,
                                           ushort* __restrict__ featT,
                                           ushort* __restrict__ featV) {
  int bid = blockIdx.x;
  int b = bid >> 9, cb = (bid >> 6) & 7, mt = bid & 63;
  int t = threadIdx.x;
  __shared__ ushort tile[64][72];

#pragma unroll
  for (int p = 0; p < 4; p++) {
    int ci = p * 16 + (t >> 4);
    int mi = (t & 15) * 4;
    float4 v = *(const float4*)&feat[((size_t)(b * 512 + cb * 64 + ci)) * 4096 + mt * 64 + mi];
    ushort4 u; u.x = f2bf(v.x); u.y = f2bf(v.y); u.z = f2bf(v.z); u.w = f2bf(v.w);
    *(ushort4*)&featV[((size_t)(b * 64 + mt) * 512 + cb * 64 + ci) * 64 + mi] = u;
    tile[ci][mi] = u.x; tile[ci][mi + 1] = u.y; tile[ci][mi + 2] = u.z; tile[ci][mi + 3] = u.w;
  }
  __syncthreads();
  int m = t >> 2, cs = (t & 3) * 16;
  ushort tmp[16];
#pragma unroll
  for (int j = 0; j < 16; j++) tmp[j] = tile[cs + j][m];
  ushort* dst = &featT[((size_t)(b * 4096 + mt * 64 + m)) * 512 + cb * 64 + cs];
  *(s8v*)dst = *(s8v*)&tmp[0];
  *(s8v*)(dst + 8) = *(s8v*)&tmp[8];
}

// ---------- k0b: cast phi_w / theta_w -> bf16 ------------------------------
__global__ __launch_bounds__(256) void k0b(const float* __restrict__ pw,
                                           const float* __restrict__ tw,
                                           ushort* __restrict__ wbp,
                                           ushort* __restrict__ wbt) {
  int bid = blockIdx.x;
  const float* src = (bid < 128) ? pw : tw;
  ushort* dst = (bid < 128) ? wbp : wbt;
  int idx = ((bid & 127) * 256 + threadIdx.x) * 4;
  float4 v = *(const float4*)&src[idx];
  ushort4 u; u.x = f2bf(v.x); u.y = f2bf(v.y); u.z = f2bf(v.z); u.w = f2bf(v.w);
  *(ushort4*)&dst[idx] = u;
}

// ---------- k0c: weight fp32 [c][d] -> weightT bf16 [d][c] -----------------
// grid 64 = 8cb x 8db
__global__ __launch_bounds__(256) void k0c(const float* __restrict__ w,
                                           ushort* __restrict__ wT) {
  int bid = blockIdx.x;
  int cb = bid >> 3, db = bid & 7;
  int t = threadIdx.x;
  __shared__ ushort tile[64][72];
#pragma unroll
  for (int p = 0; p < 4; p++) {
    int ci = p * 16 + (t >> 4);
    int di = (t & 15) * 4;
    float4 v = *(const float4*)&w[(size_t)(cb * 64 + ci) * 512 + db * 64 + di];
    tile[ci][di] = f2bf(v.x); tile[ci][di + 1] = f2bf(v.y);
    tile[ci][di + 2] = f2bf(v.z); tile[ci][di + 3] = f2bf(v.w);
  }
  __syncthreads();
  int d = t >> 2, cs = (t & 3) * 16;
  ushort tmp[16];
#pragma unroll
  for (int j = 0; j < 16; j++) tmp[j] = tile[cs + j][d];
  ushort* dst = &wT[(size_t)(db * 64 + d) * 512 + cb * 64 + cs];
  *(s8v*)dst = *(s8v*)&tmp[0];
  *(s8v*)(dst + 8) = *(s8v*)&tmp[8];
}

// ---------- k1 v2: phi/theta GEMM, 64x64 wave tiles + fused normalize ------
// grid 512 = 8b(LSB) x 2half x 32nt, block 512 = 8 waves (wn=w>>2, wi=w&3).
// Wave computes 64n x 64i: loads:MFMA = 8:16 = 0.5 (was 17:16 — each B-frag
// fed ONE MFMA; now each feeds 4 via bigger n-tile, and A-frags feed 4 via
// bigger i-tile). Row L2-norm now spans 4 waves -> cross-wave LDS reduce
// (part[128][4] = 2KB, one barrier).
__global__ __launch_bounds__(512) void k1_gemm(
    const ushort* __restrict__ featT, const ushort* __restrict__ wbp,
    const ushort* __restrict__ wbt, ushort* __restrict__ phi_n,
    ushort* __restrict__ theta_n) {
  int bid = blockIdx.x;
  int b = bid & 7;
  int rest = bid >> 3;
  int half = rest & 1;
  int nt = rest >> 1;
  const ushort* wb = half ? wbt : wbp;
  ushort* dst = half ? theta_n : phi_n;
  int t = threadIdx.x;
  int lane = t & 63, w = t >> 6;
  int col = lane & 15, quad = lane >> 4;
  int wn = w >> 2, wi = w & 3;
  int nb = nt * 128 + wn * 64;

  __shared__ float part[128][4];  // [n-local][wi] partial sum-of-squares

  const ushort* ab = featT + ((size_t)(b * 4096 + nb + col)) * 512 + quad * 8;
  const ushort* bb = wb + ((size_t)(wi * 64 + col)) * 512 + quad * 8;

  f4v acc[16];
#pragma unroll
  for (int i = 0; i < 16; i++) acc[i] = (f4v){0.f, 0.f, 0.f, 0.f};

#pragma unroll 2
  for (int kc = 0; kc < 16; kc++) {
    s8v af[4], bf[4];
#pragma unroll
    for (int rs = 0; rs < 4; rs++)
      af[rs] = *(const s8v*)(ab + (size_t)(rs * 16) * 512 + kc * 32);
#pragma unroll
    for (int ct = 0; ct < 4; ct++)
      bf[ct] = *(const s8v*)(bb + (size_t)(ct * 16) * 512 + kc * 32);
#pragma unroll
    for (int rs = 0; rs < 4; rs++)
#pragma unroll
      for (int ct = 0; ct < 4; ct++)
        acc[rs * 4 + ct] =
            __builtin_amdgcn_mfma_f32_16x16x32_bf16(af[rs], bf[ct], acc[rs * 4 + ct], 0, 0, 0);
  }

  // partial ss over this wave's 64 i, per output row (rs, reg)
#pragma unroll
  for (int rs = 0; rs < 4; rs++) {
#pragma unroll
    for (int reg = 0; reg < 4; reg++) {
      float ss = 0.f;
#pragma unroll
      for (int ct = 0; ct < 4; ct++) {
        float v = acc[rs * 4 + ct][reg];
        ss += v * v;
      }
      ss += __shfl_xor(ss, 1); ss += __shfl_xor(ss, 2);
      ss += __shfl_xor(ss, 4); ss += __shfl_xor(ss, 8);
      if (col == 0) part[wn * 64 + rs * 16 + quad * 4 + reg][wi] = ss;
    }
  }
  __syncthreads();

  float rinv[4][4];
#pragma unroll
  for (int rs = 0; rs < 4; rs++) {
#pragma unroll
    for (int reg = 0; reg < 4; reg++) {
      float4 p = *(const float4*)&part[wn * 64 + rs * 16 + quad * 4 + reg][0];
      rinv[rs][reg] = rsqrtf(p.x + p.y + p.z + p.w);
    }
  }

#pragma unroll
  for (int rs = 0; rs < 4; rs++) {
#pragma unroll
    for (int ct = 0; ct < 4; ct++) {
#pragma unroll
      for (int reg = 0; reg < 4; reg++) {
        dst[((size_t)(b * 4096 + nb + rs * 16 + quad * 4 + reg)) * 256 +
            wi * 64 + ct * 16 + col] = f2bf(acc[rs * 4 + ct][reg] * rinv[rs][reg]);
      }
    }
  }
}

// ---------- k3: MFMA flash attention (R1 champion, verbatim) ---------------
// grid 512 = 8b(LSB) x 64qt, block 512 = 8 waves, 1 block/CU (LDS ~83KB).
// 311.5us measured, VGPR 120 + 64 AGPR, no spill. Single barrier per m-tile
// (K dbuf + P dbuf). QK: mh4=w&3 (16 m-cols), rh=w>>2 (two Q sets of 16).
// PV: wave owns c [w*64,+64).
__global__ __launch_bounds__(512, 2) void k3_attn(
    const ushort* __restrict__ phi_n, const ushort* __restrict__ theta_n,
    const ushort* __restrict__ featV, ushort* __restrict__ out1) {
  int bid = blockIdx.x;
  int b = bid & 7;
  int n0 = (bid >> 3) << 6;
  int t = threadIdx.x;
  int lane = t & 63, w = t >> 6;
  int col = lane & 15, quad = lane >> 4;
  int mh4 = w & 3, rh = w >> 2;
  int l32 = lane & 31, h32 = lane >> 5;
  int cs = col & 7;

  __shared__ __align__(16) ushort ks[2 * 16384];  // [buf][row*256 + (chunk^(row&7))*8]
  __shared__ __align__(16) ushort ps[2 * 4096];   // [buf][n*64 + (chunk^(n&7))*8]
  __shared__ float dred[4 * 64];                  // [mh4][n]

  // Q A-frags, two 16-row sets: rows rh*32 + s*16 + col, k = f*32 + quad*8
  s8v qfA[8], qfB[8];
  {
    const ushort* qa = phi_n + ((size_t)(b * 4096 + n0 + rh * 32 + col)) * 256 + quad * 8;
#pragma unroll
    for (int f = 0; f < 8; f++) qfA[f] = *(const s8v*)(qa + f * 32);
    const ushort* qb = qa + 16 * 256;
#pragma unroll
    for (int f = 0; f < 8; f++) qfB[f] = *(const s8v*)(qb + f * 32);
  }

  const ushort* thb = theta_n + (size_t)b * 4096 * 256;
  const ushort* vbb = featV + (size_t)b * 64 * 512 * 64 + (size_t)(w * 64) * 64;

  f4v acc[16];
#pragma unroll
  for (int i = 0; i < 16; i++) acc[i] = (f4v){0.f, 0.f, 0.f, 0.f};
  float denp[8] = {0.f, 0.f, 0.f, 0.f, 0.f, 0.f, 0.f, 0.f};  // [set*4+r]

  // stage tile 0 into ks[0]
#pragma unroll
  for (int u = 0; u < 4; u++) {
    int row = w * 8 + u * 2 + h32;
    s8v val = *(const s8v*)(thb + (size_t)row * 256 + l32 * 8);
    *(s8v*)(ks + row * 256 + ((l32 ^ (row & 7)) * 8)) = val;
  }
  __syncthreads();

#pragma unroll 1
  for (int mt = 0; mt < 64; mt++) {
    const ushort* kc_ = ks + (mt & 1) * 16384;
    ushort* kn_ = ks + ((mt & 1) ^ 1) * 16384;
    ushort* pw_ = ps + (mt & 1) * 4096;

    // prefetch next K tile into regs (issued early, drained after exp)
    s8v kreg[4];
    if (mt < 63) {
      int m1 = (mt + 1) << 6;
#pragma unroll
      for (int u = 0; u < 4; u++) {
        int row = w * 8 + u * 2 + h32;
        kreg[u] = *(const s8v*)(thb + (size_t)(m1 + row) * 256 + l32 * 8);
      }
    }
    // V B-frags for this tile (blocked layout, 2KB window per ct-pair)
    s8v v0[4], v1[4];
    {
      const ushort* vb = vbb + (size_t)mt * 32768;
#pragma unroll
      for (int ct = 0; ct < 4; ct++) {
        const ushort* p = vb + (ct * 16 + col) * 64 + quad * 8;
        v0[ct] = *(const s8v*)p;
        v1[ct] = *(const s8v*)(p + 32);
      }
    }

    // QK: each B-frag (16 m-cols mh4*16+col) feeds both Q row-sets
    f4v svA = (f4v){0.f, 0.f, 0.f, 0.f};
    f4v svB = (f4v){0.f, 0.f, 0.f, 0.f};
    {
      const ushort* kb = kc_ + (mh4 * 16 + col) * 256;
      __builtin_amdgcn_s_setprio(1);
#pragma unroll
      for (int kk = 0; kk < 8; kk++) {
        int pos = ((kk * 4 + quad) ^ cs) * 8;
        s8v bf = *(const s8v*)(kb + pos);
        svA = __builtin_amdgcn_mfma_f32_16x16x32_bf16(qfA[kk], bf, svA, 0, 0, 0);
        svB = __builtin_amdgcn_mfma_f32_16x16x32_bf16(qfB[kk], bf, svB, 0, 0, 0);
      }
      __builtin_amdgcn_s_setprio(0);
    }

    float pA[4], pB[4];
#pragma unroll
    for (int r = 0; r < 4; r++) {
      pA[r] = __expf(svA[r]);
      pB[r] = __expf(svB[r]);
      denp[r] += pA[r];
      denp[4 + r] += pB[r];
    }

    // P -> LDS (swizzled, double-buffered): rows nA/nB, col-chunk j0 = mh4*2+(col>>3)
    {
      int j0 = mh4 * 2 + (col >> 3);
#pragma unroll
      for (int r = 0; r < 4; r++) {
        int nA = rh * 32 + quad * 4 + r;
        pw_[nA * 64 + ((j0 ^ (nA & 7)) * 8) + cs] = f2bf(pA[r]);
        int nB = nA + 16;
        pw_[nB * 64 + ((j0 ^ (nB & 7)) * 8) + cs] = f2bf(pB[r]);
      }
    }
    // write next K tile to other buffer
    if (mt < 63) {
#pragma unroll
      for (int u = 0; u < 4; u++) {
        int row = w * 8 + u * 2 + h32;
        *(s8v*)(kn_ + row * 256 + ((l32 ^ (row & 7)) * 8)) = kreg[u];
      }
    }
    __syncthreads();  // single barrier: ps[mt&1] + ks[next] ready

    // PV: A = P (all 4 rowsets), B = v0/v1 (this wave's 64-c range)
    __builtin_amdgcn_s_setprio(1);
#pragma unroll
    for (int rs = 0; rs < 4; rs++) {
      const ushort* pb = pw_ + (rs * 16 + col) * 64;
      s8v pf0 = *(const s8v*)(pb + ((quad ^ cs) * 8));
      s8v pf1 = *(const s8v*)(pb + (((quad + 4) ^ cs) * 8));
#pragma unroll
      for (int ct = 0; ct < 4; ct++) {
        acc[rs * 4 + ct] =
            __builtin_amdgcn_mfma_f32_16x16x32_bf16(pf0, v0[ct], acc[rs * 4 + ct], 0, 0, 0);
        acc[rs * 4 + ct] =
            __builtin_amdgcn_mfma_f32_16x16x32_bf16(pf1, v1[ct], acc[rs * 4 + ct], 0, 0, 0);
      }
    }
    __builtin_amdgcn_s_setprio(0);
  }

  // denominator: reduce over 16-col group, then across the 4 mh4 waves
#pragma unroll
  for (int i = 0; i < 8; i++) {
    float d = denp[i];
    d += __shfl_xor(d, 1); d += __shfl_xor(d, 2);
    d += __shfl_xor(d, 4); d += __shfl_xor(d, 8);
    denp[i] = d;
  }
  if (col == 0) {
#pragma unroll
    for (int i = 0; i < 8; i++) {
      int n = rh * 32 + (i >> 2) * 16 + quad * 4 + (i & 3);
      dred[mh4 * 64 + n] = denp[i];
    }
  }
  __syncthreads();
  if (t < 64) dred[t] = 1.0f / (dred[t] + dred[64 + t] + dred[128 + t] + dred[192 + t]);
  __syncthreads();

  // store out1 bf16 [n][c]: D[n=rs*16+quad*4+reg][c=w*64+ct*16+col]
#pragma unroll
  for (int rs = 0; rs < 4; rs++) {
#pragma unroll
    for (int ct = 0; ct < 4; ct++) {
#pragma unroll
      for (int reg = 0; reg < 4; reg++) {
        int n = rs * 16 + quad * 4 + reg;
        out1[((size_t)(b * 4096 + n0 + n)) * 512 + w * 64 + ct * 16 + col] =
            f2bf(acc[rs * 4 + ct][reg] * dred[n]);
      }
    }
  }
}

// ---------- k4: out = relu(weightT_bf @ out1^T) stored [b][d][n] fp32 ------
// grid 512 = 8b x 4dt x 16nt, block 512 = 8 waves (dw=w&1 -> 64d, nw=w>>1 -> 64n)
__global__ __launch_bounds__(512) void k4_out(
    const ushort* __restrict__ out1, const ushort* __restrict__ wT,
    float* __restrict__ out) {
  int bid = blockIdx.x;
  int b = bid & 7;
  int rest = bid >> 3;
  int dt = rest & 3;
  int nt = rest >> 2;
  int t = threadIdx.x;
  int lane = t & 63, w = t >> 6;
  int col = lane & 15, quad = lane >> 4;
  int dw = w & 1, nw = w >> 1;
  int d0 = dt * 128 + dw * 64;
  int n0 = nt * 256 + nw * 64;

  f4v acc[16];
#pragma unroll
  for (int i = 0; i < 16; i++) acc[i] = (f4v){0.f, 0.f, 0.f, 0.f};

#pragma unroll 2
  for (int kc = 0; kc < 16; kc++) {
    s8v af[4], bf[4];
#pragma unroll
    for (int rs = 0; rs < 4; rs++)
      af[rs] = *(const s8v*)(wT + (size_t)(d0 + rs * 16 + col) * 512 + kc * 32 + quad * 8);
#pragma unroll
    for (int ct = 0; ct < 4; ct++)
      bf[ct] = *(const s8v*)(out1 + ((size_t)(b * 4096 + n0 + ct * 16 + col)) * 512 +
                             kc * 32 + quad * 8);
#pragma unroll
    for (int rs = 0; rs < 4; rs++)
#pragma unroll
      for (int ct = 0; ct < 4; ct++)
        acc[rs * 4 + ct] =
            __builtin_amdgcn_mfma_f32_16x16x32_bf16(af[rs], bf[ct], acc[rs * 4 + ct], 0, 0, 0);
  }
#pragma unroll
  for (int rs = 0; rs < 4; rs++) {
#pragma unroll
    for (int ct = 0; ct < 4; ct++) {
#pragma unroll
      for (int reg = 0; reg < 4; reg++) {
        int d = d0 + rs * 16 + quad * 4 + reg;
        int n = n0 + ct * 16 + col;
        out[((size_t)(b * 512 + d)) * 4096 + n] = fmaxf(acc[rs * 4 + ct][reg], 0.f);
      }
    }
  }
}

extern "C" void kernel_launch(void* const* d_in, const int* in_sizes, int n_in,
                              void* d_out, int out_size, void* d_ws, size_t ws_size,
                              hipStream_t stream) {
  const float* feat    = (const float*)d_in[0];
  const float* phi_w   = (const float*)d_in[1];
  const float* theta_w = (const float*)d_in[2];
  const float* weight  = (const float*)d_in[3];
  float* out = (float*)d_out;

  ushort* wsu = (ushort*)d_ws;
  ushort* featT   = wsu;                    // dead after k1 -> reused as out1
  ushort* featV   = wsu + 16777216;
  ushort* phi_n   = wsu + 33554432;
  ushort* theta_n = wsu + 41943040;
  ushort* wbp     = wsu + 50331648;
  ushort* wbt     = wsu + 50462720;
  ushort* weightT = wsu + 50593792;
  ushort* out1    = wsu;                    // overlays featT

  k0a<<<dim3(4096), dim3(256), 0, stream>>>(feat, featT, featV);
  k0b<<<dim3(256), dim3(256), 0, stream>>>(phi_w, theta_w, wbp, wbt);
  k0c<<<dim3(64), dim3(256), 0, stream>>>(weight, weightT);
  k1_gemm<<<dim3(512), dim3(512), 0, stream>>>(featT, wbp, wbt, phi_n, theta_n);
  k3_attn<<<dim3(512), dim3(512), 0, stream>>>(phi_n, theta_n, featV, out1);
  k4_out<<<dim3(512), dim3(512), 0, stream>>>(out1, weightT, out);
}

// Round 9
// 533.074 us; speedup vs baseline: 1.7214x; 1.0135x over previous
//
#include <hip/hip_runtime.h>

// B=8, N=HW=4096, D=512, I=256, DO=512
// ws (ushort offsets):
//   featT  @0        [b][n=4096][c=512] bf16 (k0->k1); overlaid by out1 (k3->k4)
//   featV  @16777216 [b][mt=64][c=512][m=64] bf16 (k0->k3)
//   phi_n  @33554432 [b][n][i=256] bf16 normalized (k1->k3)
//   theta_n@41943040 same (k1->k3)
//   wb_phi @50331648 [i=256][c=512] bf16 (k0->k1)
//   wb_th  @50462720
//   weightT@50593792 [d=512][c=512] bf16 (k0->k4)
// end 50855936 ushorts = 101.7 MB (<= proven 134 MB)

typedef short s8v __attribute__((ext_vector_type(8)));
typedef float f4v __attribute__((ext_vector_type(4)));

__device__ inline ushort f2bf(float x) {
  union { float f; unsigned u; } v; v.f = x;
  unsigned u = v.u + 0x7fff + ((v.u >> 16) & 1);
  return (ushort)(u >> 16);
}

// ---------- k0 fused: all preprocessing in ONE launch ----------------------
// grid 4416 = [0,4096) k0a-body | [4096,4352) k0b-body | [4352,4416) k0c-body
// (independent work items; fusion removes 2 stream boundaries ~8us each)
__global__ __launch_bounds__(256) void k0(const float* __restrict__ feat,
                                          const float* __restrict__ pw,
                                          const float* __restrict__ tw,
                                          const float* __restrict__ w,
                                          ushort* __restrict__ featT,
                                          ushort* __restrict__ featV,
                                          ushort* __restrict__ wbp,
                                          ushort* __restrict__ wbt,
                                          ushort* __restrict__ wT) {
  int bid = blockIdx.x;
  int t = threadIdx.x;
  __shared__ ushort tile[64][72];

  if (bid < 4096) {
    // ---- k0a: feat fp32 [b][c][m] -> featV blocked bf16 + featT bf16 ----
    int b = bid >> 9, cb = (bid >> 6) & 7, mt = bid & 63;
#pragma unroll
    for (int p = 0; p < 4; p++) {
      int ci = p * 16 + (t >> 4);
      int mi = (t & 15) * 4;
      float4 v = *(const float4*)&feat[((size_t)(b * 512 + cb * 64 + ci)) * 4096 + mt * 64 + mi];
      ushort4 u; u.x = f2bf(v.x); u.y = f2bf(v.y); u.z = f2bf(v.z); u.w = f2bf(v.w);
      *(ushort4*)&featV[((size_t)(b * 64 + mt) * 512 + cb * 64 + ci) * 64 + mi] = u;
      tile[ci][mi] = u.x; tile[ci][mi + 1] = u.y; tile[ci][mi + 2] = u.z; tile[ci][mi + 3] = u.w;
    }
    __syncthreads();
    int m = t >> 2, cs = (t & 3) * 16;
    ushort tmp[16];
#pragma unroll
    for (int j = 0; j < 16; j++) tmp[j] = tile[cs + j][m];
    ushort* dst = &featT[((size_t)(b * 4096 + mt * 64 + m)) * 512 + cb * 64 + cs];
    *(s8v*)dst = *(s8v*)&tmp[0];
    *(s8v*)(dst + 8) = *(s8v*)&tmp[8];
  } else if (bid < 4352) {
    // ---- k0b: cast phi_w / theta_w -> bf16 ----
    int bb = bid - 4096;
    const float* src = (bb < 128) ? pw : tw;
    ushort* dst = (bb < 128) ? wbp : wbt;
    int idx = ((bb & 127) * 256 + t) * 4;
    float4 v = *(const float4*)&src[idx];
    ushort4 u; u.x = f2bf(v.x); u.y = f2bf(v.y); u.z = f2bf(v.z); u.w = f2bf(v.w);
    *(ushort4*)&dst[idx] = u;
  } else {
    // ---- k0c: weight fp32 [c][d] -> weightT bf16 [d][c] ----
    int bb = bid - 4352;
    int cb = bb >> 3, db = bb & 7;
#pragma unroll
    for (int p = 0; p < 4; p++) {
      int ci = p * 16 + (t >> 4);
      int di = (t & 15) * 4;
      float4 v = *(const float4*)&w[(size_t)(cb * 64 + ci) * 512 + db * 64 + di];
      tile[ci][di] = f2bf(v.x); tile[ci][di + 1] = f2bf(v.y);
      tile[ci][di + 2] = f2bf(v.z); tile[ci][di + 3] = f2bf(v.w);
    }
    __syncthreads();
    int d = t >> 2, cs = (t & 3) * 16;
    ushort tmp[16];
#pragma unroll
    for (int j = 0; j < 16; j++) tmp[j] = tile[cs + j][d];
    ushort* dst = &wT[(size_t)(db * 64 + d) * 512 + cb * 64 + cs];
    *(s8v*)dst = *(s8v*)&tmp[0];
    *(s8v*)(dst + 8) = *(s8v*)&tmp[8];
  }
}

// ---------- k1 v2: phi/theta GEMM, 64x64 wave tiles + fused normalize ------
// grid 512 = 8b(LSB) x 2half x 32nt, block 512 = 8 waves (wn=w>>2, wi=w&3).
// Wave computes 64n x 64i: loads:MFMA = 8:16 = 0.5. Row L2-norm spans 4
// waves -> cross-wave LDS reduce (part[128][4] = 2KB, one barrier).
// (R8: this version cut non-k3 time by ~60us vs the 16n x 256i layout.)
__global__ __launch_bounds__(512) void k1_gemm(
    const ushort* __restrict__ featT, const ushort* __restrict__ wbp,
    const ushort* __restrict__ wbt, ushort* __restrict__ phi_n,
    ushort* __restrict__ theta_n) {
  int bid = blockIdx.x;
  int b = bid & 7;
  int rest = bid >> 3;
  int half = rest & 1;
  int nt = rest >> 1;
  const ushort* wb = half ? wbt : wbp;
  ushort* dst = half ? theta_n : phi_n;
  int t = threadIdx.x;
  int lane = t & 63, w = t >> 6;
  int col = lane & 15, quad = lane >> 4;
  int wn = w >> 2, wi = w & 3;
  int nb = nt * 128 + wn * 64;

  __shared__ float part[128][4];  // [n-local][wi] partial sum-of-squares

  const ushort* ab = featT + ((size_t)(b * 4096 + nb + col)) * 512 + quad * 8;
  const ushort* bb = wb + ((size_t)(wi * 64 + col)) * 512 + quad * 8;

  f4v acc[16];
#pragma unroll
  for (int i = 0; i < 16; i++) acc[i] = (f4v){0.f, 0.f, 0.f, 0.f};

#pragma unroll 2
  for (int kc = 0; kc < 16; kc++) {
    s8v af[4], bf[4];
#pragma unroll
    for (int rs = 0; rs < 4; rs++)
      af[rs] = *(const s8v*)(ab + (size_t)(rs * 16) * 512 + kc * 32);
#pragma unroll
    for (int ct = 0; ct < 4; ct++)
      bf[ct] = *(const s8v*)(bb + (size_t)(ct * 16) * 512 + kc * 32);
#pragma unroll
    for (int rs = 0; rs < 4; rs++)
#pragma unroll
      for (int ct = 0; ct < 4; ct++)
        acc[rs * 4 + ct] =
            __builtin_amdgcn_mfma_f32_16x16x32_bf16(af[rs], bf[ct], acc[rs * 4 + ct], 0, 0, 0);
  }

  // partial ss over this wave's 64 i, per output row (rs, reg)
#pragma unroll
  for (int rs = 0; rs < 4; rs++) {
#pragma unroll
    for (int reg = 0; reg < 4; reg++) {
      float ss = 0.f;
#pragma unroll
      for (int ct = 0; ct < 4; ct++) {
        float v = acc[rs * 4 + ct][reg];
        ss += v * v;
      }
      ss += __shfl_xor(ss, 1); ss += __shfl_xor(ss, 2);
      ss += __shfl_xor(ss, 4); ss += __shfl_xor(ss, 8);
      if (col == 0) part[wn * 64 + rs * 16 + quad * 4 + reg][wi] = ss;
    }
  }
  __syncthreads();

  float rinv[4][4];
#pragma unroll
  for (int rs = 0; rs < 4; rs++) {
#pragma unroll
    for (int reg = 0; reg < 4; reg++) {
      float4 p = *(const float4*)&part[wn * 64 + rs * 16 + quad * 4 + reg][0];
      rinv[rs][reg] = rsqrtf(p.x + p.y + p.z + p.w);
    }
  }

#pragma unroll
  for (int rs = 0; rs < 4; rs++) {
#pragma unroll
    for (int ct = 0; ct < 4; ct++) {
#pragma unroll
      for (int reg = 0; reg < 4; reg++) {
        dst[((size_t)(b * 4096 + nb + rs * 16 + quad * 4 + reg)) * 256 +
            wi * 64 + ct * 16 + col] = f2bf(acc[rs * 4 + ct][reg] * rinv[rs][reg]);
      }
    }
  }
}

// ---------- k3: MFMA flash attention (R1 champion + 4-way QK chain split) --
// grid 512 = 8b(LSB) x 64qt, block 512 = 8 waves, 1 block/CU (LDS ~83KB).
// Baseline 314.8us, VGPR 120+64AGPR, no spill. Single barrier per m-tile
// (K dbuf + P dbuf). QK: mh4=w&3 (16 m-cols), rh=w>>2 (two Q sets of 16).
// PV: wave owns c [w*64,+64).
// NEW: QK's two 8-deep dependent MFMA chains split into 4 chains of 4
// (latency exposed at 2 waves/SIMD); +8 VGPR, 192 combined <= 256 tier.
__global__ __launch_bounds__(512, 2) void k3_attn(
    const ushort* __restrict__ phi_n, const ushort* __restrict__ theta_n,
    const ushort* __restrict__ featV, ushort* __restrict__ out1) {
  int bid = blockIdx.x;
  int b = bid & 7;
  int n0 = (bid >> 3) << 6;
  int t = threadIdx.x;
  int lane = t & 63, w = t >> 6;
  int col = lane & 15, quad = lane >> 4;
  int mh4 = w & 3, rh = w >> 2;
  int l32 = lane & 31, h32 = lane >> 5;
  int cs = col & 7;

  __shared__ __align__(16) ushort ks[2 * 16384];  // [buf][row*256 + (chunk^(row&7))*8]
  __shared__ __align__(16) ushort ps[2 * 4096];   // [buf][n*64 + (chunk^(n&7))*8]
  __shared__ float dred[4 * 64];                  // [mh4][n]

  // Q A-frags, two 16-row sets: rows rh*32 + s*16 + col, k = f*32 + quad*8
  s8v qfA[8], qfB[8];
  {
    const ushort* qa = phi_n + ((size_t)(b * 4096 + n0 + rh * 32 + col)) * 256 + quad * 8;
#pragma unroll
    for (int f = 0; f < 8; f++) qfA[f] = *(const s8v*)(qa + f * 32);
    const ushort* qb = qa + 16 * 256;
#pragma unroll
    for (int f = 0; f < 8; f++) qfB[f] = *(const s8v*)(qb + f * 32);
  }

  const ushort* thb = theta_n + (size_t)b * 4096 * 256;
  const ushort* vbb = featV + (size_t)b * 64 * 512 * 64 + (size_t)(w * 64) * 64;

  f4v acc[16];
#pragma unroll
  for (int i = 0; i < 16; i++) acc[i] = (f4v){0.f, 0.f, 0.f, 0.f};
  float denp[8] = {0.f, 0.f, 0.f, 0.f, 0.f, 0.f, 0.f, 0.f};  // [set*4+r]

  // stage tile 0 into ks[0]
#pragma unroll
  for (int u = 0; u < 4; u++) {
    int row = w * 8 + u * 2 + h32;
    s8v val = *(const s8v*)(thb + (size_t)row * 256 + l32 * 8);
    *(s8v*)(ks + row * 256 + ((l32 ^ (row & 7)) * 8)) = val;
  }
  __syncthreads();

#pragma unroll 1
  for (int mt = 0; mt < 64; mt++) {
    const ushort* kc_ = ks + (mt & 1) * 16384;
    ushort* kn_ = ks + ((mt & 1) ^ 1) * 16384;
    ushort* pw_ = ps + (mt & 1) * 4096;

    // prefetch next K tile into regs (issued early, drained after exp)
    s8v kreg[4];
    if (mt < 63) {
      int m1 = (mt + 1) << 6;
#pragma unroll
      for (int u = 0; u < 4; u++) {
        int row = w * 8 + u * 2 + h32;
        kreg[u] = *(const s8v*)(thb + (size_t)(m1 + row) * 256 + l32 * 8);
      }
    }
    // V B-frags for this tile (blocked layout, 2KB window per ct-pair)
    s8v v0[4], v1[4];
    {
      const ushort* vb = vbb + (size_t)mt * 32768;
#pragma unroll
      for (int ct = 0; ct < 4; ct++) {
        const ushort* p = vb + (ct * 16 + col) * 64 + quad * 8;
        v0[ct] = *(const s8v*)p;
        v1[ct] = *(const s8v*)(p + 32);
      }
    }

    // QK: 4 independent chains of 4 (was 2 chains of 8 — latency exposed
    // at 2 waves/SIMD); each B-frag still feeds both Q row-sets.
    f4v svA0 = (f4v){0.f, 0.f, 0.f, 0.f}, svA1 = (f4v){0.f, 0.f, 0.f, 0.f};
    f4v svB0 = (f4v){0.f, 0.f, 0.f, 0.f}, svB1 = (f4v){0.f, 0.f, 0.f, 0.f};
    {
      const ushort* kb = kc_ + (mh4 * 16 + col) * 256;
      __builtin_amdgcn_s_setprio(1);
#pragma unroll
      for (int kk = 0; kk < 8; kk += 2) {
        int pos0 = ((kk * 4 + quad) ^ cs) * 8;
        int pos1 = (((kk + 1) * 4 + quad) ^ cs) * 8;
        s8v bf0 = *(const s8v*)(kb + pos0);
        s8v bf1 = *(const s8v*)(kb + pos1);
        svA0 = __builtin_amdgcn_mfma_f32_16x16x32_bf16(qfA[kk], bf0, svA0, 0, 0, 0);
        svB0 = __builtin_amdgcn_mfma_f32_16x16x32_bf16(qfB[kk], bf0, svB0, 0, 0, 0);
        svA1 = __builtin_amdgcn_mfma_f32_16x16x32_bf16(qfA[kk + 1], bf1, svA1, 0, 0, 0);
        svB1 = __builtin_amdgcn_mfma_f32_16x16x32_bf16(qfB[kk + 1], bf1, svB1, 0, 0, 0);
      }
      __builtin_amdgcn_s_setprio(0);
    }

    float pA[4], pB[4];
#pragma unroll
    for (int r = 0; r < 4; r++) {
      pA[r] = __expf(svA0[r] + svA1[r]);
      pB[r] = __expf(svB0[r] + svB1[r]);
      denp[r] += pA[r];
      denp[4 + r] += pB[r];
    }

    // P -> LDS (swizzled, double-buffered): rows nA/nB, col-chunk j0 = mh4*2+(col>>3)
    {
      int j0 = mh4 * 2 + (col >> 3);
#pragma unroll
      for (int r = 0; r < 4; r++) {
        int nA = rh * 32 + quad * 4 + r;
        pw_[nA * 64 + ((j0 ^ (nA & 7)) * 8) + cs] = f2bf(pA[r]);
        int nB = nA + 16;
        pw_[nB * 64 + ((j0 ^ (nB & 7)) * 8) + cs] = f2bf(pB[r]);
      }
    }
    // write next K tile to other buffer
    if (mt < 63) {
#pragma unroll
      for (int u = 0; u < 4; u++) {
        int row = w * 8 + u * 2 + h32;
        *(s8v*)(kn_ + row * 256 + ((l32 ^ (row & 7)) * 8)) = kreg[u];
      }
    }
    __syncthreads();  // single barrier: ps[mt&1] + ks[next] ready

    // PV: A = P (all 4 rowsets), B = v0/v1 (this wave's 64-c range)
    __builtin_amdgcn_s_setprio(1);
#pragma unroll
    for (int rs = 0; rs < 4; rs++) {
      const ushort* pb = pw_ + (rs * 16 + col) * 64;
      s8v pf0 = *(const s8v*)(pb + ((quad ^ cs) * 8));
      s8v pf1 = *(const s8v*)(pb + (((quad + 4) ^ cs) * 8));
#pragma unroll
      for (int ct = 0; ct < 4; ct++) {
        acc[rs * 4 + ct] =
            __builtin_amdgcn_mfma_f32_16x16x32_bf16(pf0, v0[ct], acc[rs * 4 + ct], 0, 0, 0);
        acc[rs * 4 + ct] =
            __builtin_amdgcn_mfma_f32_16x16x32_bf16(pf1, v1[ct], acc[rs * 4 + ct], 0, 0, 0);
      }
    }
    __builtin_amdgcn_s_setprio(0);
  }

  // denominator: reduce over 16-col group, then across the 4 mh4 waves
#pragma unroll
  for (int i = 0; i < 8; i++) {
    float d = denp[i];
    d += __shfl_xor(d, 1); d += __shfl_xor(d, 2);
    d += __shfl_xor(d, 4); d += __shfl_xor(d, 8);
    denp[i] = d;
  }
  if (col == 0) {
#pragma unroll
    for (int i = 0; i < 8; i++) {
      int n = rh * 32 + (i >> 2) * 16 + quad * 4 + (i & 3);
      dred[mh4 * 64 + n] = denp[i];
    }
  }
  __syncthreads();
  if (t < 64) dred[t] = 1.0f / (dred[t] + dred[64 + t] + dred[128 + t] + dred[192 + t]);
  __syncthreads();

  // store out1 bf16 [n][c]: D[n=rs*16+quad*4+reg][c=w*64+ct*16+col]
#pragma unroll
  for (int rs = 0; rs < 4; rs++) {
#pragma unroll
    for (int ct = 0; ct < 4; ct++) {
#pragma unroll
      for (int reg = 0; reg < 4; reg++) {
        int n = rs * 16 + quad * 4 + reg;
        out1[((size_t)(b * 4096 + n0 + n)) * 512 + w * 64 + ct * 16 + col] =
            f2bf(acc[rs * 4 + ct][reg] * dred[n]);
      }
    }
  }
}

// ---------- k4: out = relu(weightT_bf @ out1^T) stored [b][d][n] fp32 ------
// grid 512 = 8b x 4dt x 16nt, block 512 = 8 waves (dw=w&1 -> 64d, nw=w>>1 -> 64n)
__global__ __launch_bounds__(512) void k4_out(
    const ushort* __restrict__ out1, const ushort* __restrict__ wT,
    float* __restrict__ out) {
  int bid = blockIdx.x;
  int b = bid & 7;
  int rest = bid >> 3;
  int dt = rest & 3;
  int nt = rest >> 2;
  int t = threadIdx.x;
  int lane = t & 63, w = t >> 6;
  int col = lane & 15, quad = lane >> 4;
  int dw = w & 1, nw = w >> 1;
  int d0 = dt * 128 + dw * 64;
  int n0 = nt * 256 + nw * 64;

  f4v acc[16];
#pragma unroll
  for (int i = 0; i < 16; i++) acc[i] = (f4v){0.f, 0.f, 0.f, 0.f};

#pragma unroll 2
  for (int kc = 0; kc < 16; kc++) {
    s8v af[4], bf[4];
#pragma unroll
    for (int rs = 0; rs < 4; rs++)
      af[rs] = *(const s8v*)(wT + (size_t)(d0 + rs * 16 + col) * 512 + kc * 32 + quad * 8);
#pragma unroll
    for (int ct = 0; ct < 4; ct++)
      bf[ct] = *(const s8v*)(out1 + ((size_t)(b * 4096 + n0 + ct * 16 + col)) * 512 +
                             kc * 32 + quad * 8);
#pragma unroll
    for (int rs = 0; rs < 4; rs++)
#pragma unroll
      for (int ct = 0; ct < 4; ct++)
        acc[rs * 4 + ct] =
            __builtin_amdgcn_mfma_f32_16x16x32_bf16(af[rs], bf[ct], acc[rs * 4 + ct], 0, 0, 0);
  }
#pragma unroll
  for (int rs = 0; rs < 4; rs++) {
#pragma unroll
    for (int ct = 0; ct < 4; ct++) {
#pragma unroll
      for (int reg = 0; reg < 4; reg++) {
        int d = d0 + rs * 16 + quad * 4 + reg;
        int n = n0 + ct * 16 + col;
        out[((size_t)(b * 512 + d)) * 4096 + n] = fmaxf(acc[rs * 4 + ct][reg], 0.f);
      }
    }
  }
}

extern "C" void kernel_launch(void* const* d_in, const int* in_sizes, int n_in,
                              void* d_out, int out_size, void* d_ws, size_t ws_size,
                              hipStream_t stream) {
  const float* feat    = (const float*)d_in[0];
  const float* phi_w   = (const float*)d_in[1];
  const float* theta_w = (const float*)d_in[2];
  const float* weight  = (const float*)d_in[3];
  float* out = (float*)d_out;

  ushort* wsu = (ushort*)d_ws;
  ushort* featT   = wsu;                    // dead after k1 -> reused as out1
  ushort* featV   = wsu + 16777216;
  ushort* phi_n   = wsu + 33554432;
  ushort* theta_n = wsu + 41943040;
  ushort* wbp     = wsu + 50331648;
  ushort* wbt     = wsu + 50462720;
  ushort* weightT = wsu + 50593792;
  ushort* out1    = wsu;                    // overlays featT

  k0<<<dim3(4416), dim3(256), 0, stream>>>(feat, phi_w, theta_w, weight,
                                           featT, featV, wbp, wbt, weightT);
  k1_gemm<<<dim3(512), dim3(512), 0, stream>>>(featT, wbp, wbt, phi_n, theta_n);
  k3_attn<<<dim3(512), dim3(512), 0, stream>>>(phi_n, theta_n, featV, out1);
  k4_out<<<dim3(512), dim3(512), 0, stream>>>(out1, weightT, out);
}

// Round 10
// 530.406 us; speedup vs baseline: 1.7301x; 1.0050x over previous
//
#include <hip/hip_runtime.h>

// B=8, N=HW=4096, D=512, I=256, DO=512
// ws (ushort offsets):
//   featT  @0        [b][n=4096][c=512] bf16 (k0->k1); overlaid by out1 (k3->k4)
//   featV  @16777216 [b][mt=64][c=512][m=64] bf16 (k0->k3)
//   phi_n  @33554432 [b][n][i=256] bf16 normalized (k1->k3)
//   theta_n@41943040 same (k1->k3)
//   wb_phi @50331648 [i=256][c=512] bf16 (k0->k1)
//   wb_th  @50462720
//   weightT@50593792 [d=512][c=512] bf16 (k0->k4)
// end 50855936 ushorts = 101.7 MB (<= proven 134 MB)

typedef short s8v __attribute__((ext_vector_type(8)));
typedef float f4v __attribute__((ext_vector_type(4)));

__device__ inline ushort f2bf(float x) {
  union { float f; unsigned u; } v; v.f = x;
  unsigned u = v.u + 0x7fff + ((v.u >> 16) & 1);
  return (ushort)(u >> 16);
}

// ---------- k0 fused: all preprocessing in ONE launch ----------------------
// grid 4416 = [0,4096) k0a-body | [4096,4352) k0b-body | [4352,4416) k0c-body
__global__ __launch_bounds__(256) void k0(const float* __restrict__ feat,
                                          const float* __restrict__ pw,
                                          const float* __restrict__ tw,
                                          const float* __restrict__ w,
                                          ushort* __restrict__ featT,
                                          ushort* __restrict__ featV,
                                          ushort* __restrict__ wbp,
                                          ushort* __restrict__ wbt,
                                          ushort* __restrict__ wT) {
  int bid = blockIdx.x;
  int t = threadIdx.x;
  __shared__ ushort tile[64][72];

  if (bid < 4096) {
    // ---- k0a: feat fp32 [b][c][m] -> featV blocked bf16 + featT bf16 ----
    int b = bid >> 9, cb = (bid >> 6) & 7, mt = bid & 63;
#pragma unroll
    for (int p = 0; p < 4; p++) {
      int ci = p * 16 + (t >> 4);
      int mi = (t & 15) * 4;
      float4 v = *(const float4*)&feat[((size_t)(b * 512 + cb * 64 + ci)) * 4096 + mt * 64 + mi];
      ushort4 u; u.x = f2bf(v.x); u.y = f2bf(v.y); u.z = f2bf(v.z); u.w = f2bf(v.w);
      *(ushort4*)&featV[((size_t)(b * 64 + mt) * 512 + cb * 64 + ci) * 64 + mi] = u;
      tile[ci][mi] = u.x; tile[ci][mi + 1] = u.y; tile[ci][mi + 2] = u.z; tile[ci][mi + 3] = u.w;
    }
    __syncthreads();
    int m = t >> 2, cs = (t & 3) * 16;
    ushort tmp[16];
#pragma unroll
    for (int j = 0; j < 16; j++) tmp[j] = tile[cs + j][m];
    ushort* dst = &featT[((size_t)(b * 4096 + mt * 64 + m)) * 512 + cb * 64 + cs];
    *(s8v*)dst = *(s8v*)&tmp[0];
    *(s8v*)(dst + 8) = *(s8v*)&tmp[8];
  } else if (bid < 4352) {
    // ---- k0b: cast phi_w / theta_w -> bf16 ----
    int bb = bid - 4096;
    const float* src = (bb < 128) ? pw : tw;
    ushort* dst = (bb < 128) ? wbp : wbt;
    int idx = ((bb & 127) * 256 + t) * 4;
    float4 v = *(const float4*)&src[idx];
    ushort4 u; u.x = f2bf(v.x); u.y = f2bf(v.y); u.z = f2bf(v.z); u.w = f2bf(v.w);
    *(ushort4*)&dst[idx] = u;
  } else {
    // ---- k0c: weight fp32 [c][d] -> weightT bf16 [d][c] ----
    int bb = bid - 4352;
    int cb = bb >> 3, db = bb & 7;
#pragma unroll
    for (int p = 0; p < 4; p++) {
      int ci = p * 16 + (t >> 4);
      int di = (t & 15) * 4;
      float4 v = *(const float4*)&w[(size_t)(cb * 64 + ci) * 512 + db * 64 + di];
      tile[ci][di] = f2bf(v.x); tile[ci][di + 1] = f2bf(v.y);
      tile[ci][di + 2] = f2bf(v.z); tile[ci][di + 3] = f2bf(v.w);
    }
    __syncthreads();
    int d = t >> 2, cs = (t & 3) * 16;
    ushort tmp[16];
#pragma unroll
    for (int j = 0; j < 16; j++) tmp[j] = tile[cs + j][d];
    ushort* dst = &wT[(size_t)(db * 64 + d) * 512 + cb * 64 + cs];
    *(s8v*)dst = *(s8v*)&tmp[0];
    *(s8v*)(dst + 8) = *(s8v*)&tmp[8];
  }
}

// ---------- k1 v3: 64x64 wave tiles + cross-iter fragment pipeline ---------
// grid 512 = 8b(LSB) x 2half x 32nt, block 512 = 8 waves (wn=w>>2, wi=w&3).
// L2-latency-bound before (8 loads @~200cyc vs 78cyc MFMA per kc): explicit
// ping-pong prefetch (afA/bfA <-> afB/bfB, static names) hides the latency.
__global__ __launch_bounds__(512) void k1_gemm(
    const ushort* __restrict__ featT, const ushort* __restrict__ wbp,
    const ushort* __restrict__ wbt, ushort* __restrict__ phi_n,
    ushort* __restrict__ theta_n) {
  int bid = blockIdx.x;
  int b = bid & 7;
  int rest = bid >> 3;
  int half = rest & 1;
  int nt = rest >> 1;
  const ushort* wb = half ? wbt : wbp;
  ushort* dst = half ? theta_n : phi_n;
  int t = threadIdx.x;
  int lane = t & 63, w = t >> 6;
  int col = lane & 15, quad = lane >> 4;
  int wn = w >> 2, wi = w & 3;
  int nb = nt * 128 + wn * 64;

  __shared__ float part[128][4];  // [n-local][wi] partial sum-of-squares

  const ushort* ab = featT + ((size_t)(b * 4096 + nb + col)) * 512 + quad * 8;
  const ushort* bb = wb + ((size_t)(wi * 64 + col)) * 512 + quad * 8;

  f4v acc[16];
#pragma unroll
  for (int i = 0; i < 16; i++) acc[i] = (f4v){0.f, 0.f, 0.f, 0.f};

  s8v afA[4], bfA[4], afB[4], bfB[4];
#pragma unroll
  for (int rs = 0; rs < 4; rs++) afA[rs] = *(const s8v*)(ab + (size_t)(rs * 16) * 512);
#pragma unroll
  for (int ct = 0; ct < 4; ct++) bfA[ct] = *(const s8v*)(bb + (size_t)(ct * 16) * 512);

#pragma unroll 1
  for (int kc = 0; kc < 16; kc += 2) {
#pragma unroll
    for (int rs = 0; rs < 4; rs++)
      afB[rs] = *(const s8v*)(ab + (size_t)(rs * 16) * 512 + (kc + 1) * 32);
#pragma unroll
    for (int ct = 0; ct < 4; ct++)
      bfB[ct] = *(const s8v*)(bb + (size_t)(ct * 16) * 512 + (kc + 1) * 32);
#pragma unroll
    for (int rs = 0; rs < 4; rs++)
#pragma unroll
      for (int ct = 0; ct < 4; ct++)
        acc[rs * 4 + ct] =
            __builtin_amdgcn_mfma_f32_16x16x32_bf16(afA[rs], bfA[ct], acc[rs * 4 + ct], 0, 0, 0);
    if (kc + 2 < 16) {
#pragma unroll
      for (int rs = 0; rs < 4; rs++)
        afA[rs] = *(const s8v*)(ab + (size_t)(rs * 16) * 512 + (kc + 2) * 32);
#pragma unroll
      for (int ct = 0; ct < 4; ct++)
        bfA[ct] = *(const s8v*)(bb + (size_t)(ct * 16) * 512 + (kc + 2) * 32);
    }
#pragma unroll
    for (int rs = 0; rs < 4; rs++)
#pragma unroll
      for (int ct = 0; ct < 4; ct++)
        acc[rs * 4 + ct] =
            __builtin_amdgcn_mfma_f32_16x16x32_bf16(afB[rs], bfB[ct], acc[rs * 4 + ct], 0, 0, 0);
  }

  // partial ss over this wave's 64 i, per output row (rs, reg)
#pragma unroll
  for (int rs = 0; rs < 4; rs++) {
#pragma unroll
    for (int reg = 0; reg < 4; reg++) {
      float ss = 0.f;
#pragma unroll
      for (int ct = 0; ct < 4; ct++) {
        float v = acc[rs * 4 + ct][reg];
        ss += v * v;
      }
      ss += __shfl_xor(ss, 1); ss += __shfl_xor(ss, 2);
      ss += __shfl_xor(ss, 4); ss += __shfl_xor(ss, 8);
      if (col == 0) part[wn * 64 + rs * 16 + quad * 4 + reg][wi] = ss;
    }
  }
  __syncthreads();

  float rinv[4][4];
#pragma unroll
  for (int rs = 0; rs < 4; rs++) {
#pragma unroll
    for (int reg = 0; reg < 4; reg++) {
      float4 p = *(const float4*)&part[wn * 64 + rs * 16 + quad * 4 + reg][0];
      rinv[rs][reg] = rsqrtf(p.x + p.y + p.z + p.w);
    }
  }

#pragma unroll
  for (int rs = 0; rs < 4; rs++) {
#pragma unroll
    for (int ct = 0; ct < 4; ct++) {
#pragma unroll
      for (int reg = 0; reg < 4; reg++) {
        dst[((size_t)(b * 4096 + nb + rs * 16 + quad * 4 + reg)) * 256 +
            wi * 64 + ct * 16 + col] = f2bf(acc[rs * 4 + ct][reg] * rinv[rs][reg]);
      }
    }
  }
}

// ---------- k3: MFMA flash attention (champion + relaxed main-loop barrier) -
// grid 512 = 8b(LSB) x 64qt, block 512 = 8 waves, 1 block/CU (LDS ~83KB).
// NEW: main-loop barrier = lgkmcnt(0)-only + raw s_barrier (no vmcnt drain):
// V-fragment global loads stay in flight across the barrier; the compiler's
// own vmcnt(N) waits cover their first PV use. LDS visibility (ps + K-tile
// ds_writes) is fully covered by lgkmcnt(0). All ks/ps WAR hazards retire at
// a barrier whose preceding lgkmcnt(0) drains the reads. (T4-lite; m97-drain
// was the measured ~20% stall mechanism.)
__global__ __launch_bounds__(512, 2) void k3_attn(
    const ushort* __restrict__ phi_n, const ushort* __restrict__ theta_n,
    const ushort* __restrict__ featV, ushort* __restrict__ out1) {
  int bid = blockIdx.x;
  int b = bid & 7;
  int n0 = (bid >> 3) << 6;
  int t = threadIdx.x;
  int lane = t & 63, w = t >> 6;
  int col = lane & 15, quad = lane >> 4;
  int mh4 = w & 3, rh = w >> 2;
  int l32 = lane & 31, h32 = lane >> 5;
  int cs = col & 7;

  __shared__ __align__(16) ushort ks[2 * 16384];  // [buf][row*256 + (chunk^(row&7))*8]
  __shared__ __align__(16) ushort ps[2 * 4096];   // [buf][n*64 + (chunk^(n&7))*8]
  __shared__ float dred[4 * 64];                  // [mh4][n]

  // Q A-frags, two 16-row sets: rows rh*32 + s*16 + col, k = f*32 + quad*8
  s8v qfA[8], qfB[8];
  {
    const ushort* qa = phi_n + ((size_t)(b * 4096 + n0 + rh * 32 + col)) * 256 + quad * 8;
#pragma unroll
    for (int f = 0; f < 8; f++) qfA[f] = *(const s8v*)(qa + f * 32);
    const ushort* qb = qa + 16 * 256;
#pragma unroll
    for (int f = 0; f < 8; f++) qfB[f] = *(const s8v*)(qb + f * 32);
  }

  const ushort* thb = theta_n + (size_t)b * 4096 * 256;
  const ushort* vbb = featV + (size_t)b * 64 * 512 * 64 + (size_t)(w * 64) * 64;

  f4v acc[16];
#pragma unroll
  for (int i = 0; i < 16; i++) acc[i] = (f4v){0.f, 0.f, 0.f, 0.f};
  float denp[8] = {0.f, 0.f, 0.f, 0.f, 0.f, 0.f, 0.f, 0.f};  // [set*4+r]

  // stage tile 0 into ks[0]
#pragma unroll
  for (int u = 0; u < 4; u++) {
    int row = w * 8 + u * 2 + h32;
    s8v val = *(const s8v*)(thb + (size_t)row * 256 + l32 * 8);
    *(s8v*)(ks + row * 256 + ((l32 ^ (row & 7)) * 8)) = val;
  }
  __syncthreads();

#pragma unroll 1
  for (int mt = 0; mt < 64; mt++) {
    const ushort* kc_ = ks + (mt & 1) * 16384;
    ushort* kn_ = ks + ((mt & 1) ^ 1) * 16384;
    ushort* pw_ = ps + (mt & 1) * 4096;

    // prefetch next K tile into regs (issued early, drained after exp)
    s8v kreg[4];
    if (mt < 63) {
      int m1 = (mt + 1) << 6;
#pragma unroll
      for (int u = 0; u < 4; u++) {
        int row = w * 8 + u * 2 + h32;
        kreg[u] = *(const s8v*)(thb + (size_t)(m1 + row) * 256 + l32 * 8);
      }
    }
    // V B-frags for this tile (blocked layout; consumed AFTER the barrier —
    // relaxed barrier lets these stay in flight across it)
    s8v v0[4], v1[4];
    {
      const ushort* vb = vbb + (size_t)mt * 32768;
#pragma unroll
      for (int ct = 0; ct < 4; ct++) {
        const ushort* p = vb + (ct * 16 + col) * 64 + quad * 8;
        v0[ct] = *(const s8v*)p;
        v1[ct] = *(const s8v*)(p + 32);
      }
    }

    // QK: 4 independent chains of 4; each B-frag feeds both Q row-sets
    f4v svA0 = (f4v){0.f, 0.f, 0.f, 0.f}, svA1 = (f4v){0.f, 0.f, 0.f, 0.f};
    f4v svB0 = (f4v){0.f, 0.f, 0.f, 0.f}, svB1 = (f4v){0.f, 0.f, 0.f, 0.f};
    {
      const ushort* kb = kc_ + (mh4 * 16 + col) * 256;
      __builtin_amdgcn_s_setprio(1);
#pragma unroll
      for (int kk = 0; kk < 8; kk += 2) {
        int pos0 = ((kk * 4 + quad) ^ cs) * 8;
        int pos1 = (((kk + 1) * 4 + quad) ^ cs) * 8;
        s8v bf0 = *(const s8v*)(kb + pos0);
        s8v bf1 = *(const s8v*)(kb + pos1);
        svA0 = __builtin_amdgcn_mfma_f32_16x16x32_bf16(qfA[kk], bf0, svA0, 0, 0, 0);
        svB0 = __builtin_amdgcn_mfma_f32_16x16x32_bf16(qfB[kk], bf0, svB0, 0, 0, 0);
        svA1 = __builtin_amdgcn_mfma_f32_16x16x32_bf16(qfA[kk + 1], bf1, svA1, 0, 0, 0);
        svB1 = __builtin_amdgcn_mfma_f32_16x16x32_bf16(qfB[kk + 1], bf1, svB1, 0, 0, 0);
      }
      __builtin_amdgcn_s_setprio(0);
    }

    float pA[4], pB[4];
#pragma unroll
    for (int r = 0; r < 4; r++) {
      pA[r] = __expf(svA0[r] + svA1[r]);
      pB[r] = __expf(svB0[r] + svB1[r]);
      denp[r] += pA[r];
      denp[4 + r] += pB[r];
    }

    // P -> LDS (swizzled, double-buffered): rows nA/nB, col-chunk j0 = mh4*2+(col>>3)
    {
      int j0 = mh4 * 2 + (col >> 3);
#pragma unroll
      for (int r = 0; r < 4; r++) {
        int nA = rh * 32 + quad * 4 + r;
        pw_[nA * 64 + ((j0 ^ (nA & 7)) * 8) + cs] = f2bf(pA[r]);
        int nB = nA + 16;
        pw_[nB * 64 + ((j0 ^ (nB & 7)) * 8) + cs] = f2bf(pB[r]);
      }
    }
    // write next K tile to other buffer
    if (mt < 63) {
#pragma unroll
      for (int u = 0; u < 4; u++) {
        int row = w * 8 + u * 2 + h32;
        *(s8v*)(kn_ + row * 256 + ((l32 ^ (row & 7)) * 8)) = kreg[u];
      }
    }
    // relaxed barrier: drain DS only (ps + ks writes visible); V loads
    // remain in flight — compiler waits vmcnt(N) at their first PV use.
    asm volatile("s_waitcnt lgkmcnt(0)" ::: "memory");
    __builtin_amdgcn_s_barrier();

    // PV: A = P (all 4 rowsets), B = v0/v1 (this wave's 64-c range)
    __builtin_amdgcn_s_setprio(1);
#pragma unroll
    for (int rs = 0; rs < 4; rs++) {
      const ushort* pb = pw_ + (rs * 16 + col) * 64;
      s8v pf0 = *(const s8v*)(pb + ((quad ^ cs) * 8));
      s8v pf1 = *(const s8v*)(pb + (((quad + 4) ^ cs) * 8));
#pragma unroll
      for (int ct = 0; ct < 4; ct++) {
        acc[rs * 4 + ct] =
            __builtin_amdgcn_mfma_f32_16x16x32_bf16(pf0, v0[ct], acc[rs * 4 + ct], 0, 0, 0);
        acc[rs * 4 + ct] =
            __builtin_amdgcn_mfma_f32_16x16x32_bf16(pf1, v1[ct], acc[rs * 4 + ct], 0, 0, 0);
      }
    }
    __builtin_amdgcn_s_setprio(0);
  }

  // denominator: reduce over 16-col group, then across the 4 mh4 waves
#pragma unroll
  for (int i = 0; i < 8; i++) {
    float d = denp[i];
    d += __shfl_xor(d, 1); d += __shfl_xor(d, 2);
    d += __shfl_xor(d, 4); d += __shfl_xor(d, 8);
    denp[i] = d;
  }
  if (col == 0) {
#pragma unroll
    for (int i = 0; i < 8; i++) {
      int n = rh * 32 + (i >> 2) * 16 + quad * 4 + (i & 3);
      dred[mh4 * 64 + n] = denp[i];
    }
  }
  __syncthreads();
  if (t < 64) dred[t] = 1.0f / (dred[t] + dred[64 + t] + dred[128 + t] + dred[192 + t]);
  __syncthreads();

  // store out1 bf16 [n][c]: D[n=rs*16+quad*4+reg][c=w*64+ct*16+col]
#pragma unroll
  for (int rs = 0; rs < 4; rs++) {
#pragma unroll
    for (int ct = 0; ct < 4; ct++) {
#pragma unroll
      for (int reg = 0; reg < 4; reg++) {
        int n = rs * 16 + quad * 4 + reg;
        out1[((size_t)(b * 4096 + n0 + n)) * 512 + w * 64 + ct * 16 + col] =
            f2bf(acc[rs * 4 + ct][reg] * dred[n]);
      }
    }
  }
}

// ---------- k4 v2: relu(weightT_bf @ out1^T) + cross-iter fragment pipeline -
// grid 512 = 8b x 4dt x 16nt, block 512 = 8 waves (dw=w&1 -> 64d, nw=w>>1 -> 64n)
__global__ __launch_bounds__(512) void k4_out(
    const ushort* __restrict__ out1, const ushort* __restrict__ wT,
    float* __restrict__ out) {
  int bid = blockIdx.x;
  int b = bid & 7;
  int rest = bid >> 3;
  int dt = rest & 3;
  int nt = rest >> 2;
  int t = threadIdx.x;
  int lane = t & 63, w = t >> 6;
  int col = lane & 15, quad = lane >> 4;
  int dw = w & 1, nw = w >> 1;
  int d0 = dt * 128 + dw * 64;
  int n0 = nt * 256 + nw * 64;

  const ushort* ab = wT + (size_t)(d0 + col) * 512 + quad * 8;
  const ushort* bb = out1 + ((size_t)(b * 4096 + n0 + col)) * 512 + quad * 8;

  f4v acc[16];
#pragma unroll
  for (int i = 0; i < 16; i++) acc[i] = (f4v){0.f, 0.f, 0.f, 0.f};

  s8v afA[4], bfA[4], afB[4], bfB[4];
#pragma unroll
  for (int rs = 0; rs < 4; rs++) afA[rs] = *(const s8v*)(ab + (size_t)(rs * 16) * 512);
#pragma unroll
  for (int ct = 0; ct < 4; ct++) bfA[ct] = *(const s8v*)(bb + (size_t)(ct * 16) * 512);

#pragma unroll 1
  for (int kc = 0; kc < 16; kc += 2) {
#pragma unroll
    for (int rs = 0; rs < 4; rs++)
      afB[rs] = *(const s8v*)(ab + (size_t)(rs * 16) * 512 + (kc + 1) * 32);
#pragma unroll
    for (int ct = 0; ct < 4; ct++)
      bfB[ct] = *(const s8v*)(bb + (size_t)(ct * 16) * 512 + (kc + 1) * 32);
#pragma unroll
    for (int rs = 0; rs < 4; rs++)
#pragma unroll
      for (int ct = 0; ct < 4; ct++)
        acc[rs * 4 + ct] =
            __builtin_amdgcn_mfma_f32_16x16x32_bf16(afA[rs], bfA[ct], acc[rs * 4 + ct], 0, 0, 0);
    if (kc + 2 < 16) {
#pragma unroll
      for (int rs = 0; rs < 4; rs++)
        afA[rs] = *(const s8v*)(ab + (size_t)(rs * 16) * 512 + (kc + 2) * 32);
#pragma unroll
      for (int ct = 0; ct < 4; ct++)
        bfA[ct] = *(const s8v*)(bb + (size_t)(ct * 16) * 512 + (kc + 2) * 32);
    }
#pragma unroll
    for (int rs = 0; rs < 4; rs++)
#pragma unroll
      for (int ct = 0; ct < 4; ct++)
        acc[rs * 4 + ct] =
            __builtin_amdgcn_mfma_f32_16x16x32_bf16(afB[rs], bfB[ct], acc[rs * 4 + ct], 0, 0, 0);
  }

#pragma unroll
  for (int rs = 0; rs < 4; rs++) {
#pragma unroll
    for (int ct = 0; ct < 4; ct++) {
#pragma unroll
      for (int reg = 0; reg < 4; reg++) {
        int d = d0 + rs * 16 + quad * 4 + reg;
        int n = n0 + ct * 16 + col;
        out[((size_t)(b * 512 + d)) * 4096 + n] = fmaxf(acc[rs * 4 + ct][reg], 0.f);
      }
    }
  }
}

extern "C" void kernel_launch(void* const* d_in, const int* in_sizes, int n_in,
                              void* d_out, int out_size, void* d_ws, size_t ws_size,
                              hipStream_t stream) {
  const float* feat    = (const float*)d_in[0];
  const float* phi_w   = (const float*)d_in[1];
  const float* theta_w = (const float*)d_in[2];
  const float* weight  = (const float*)d_in[3];
  float* out = (float*)d_out;

  ushort* wsu = (ushort*)d_ws;
  ushort* featT   = wsu;                    // dead after k1 -> reused as out1
  ushort* featV   = wsu + 16777216;
  ushort* phi_n   = wsu + 33554432;
  ushort* theta_n = wsu + 41943040;
  ushort* wbp     = wsu + 50331648;
  ushort* wbt     = wsu + 50462720;
  ushort* weightT = wsu + 50593792;
  ushort* out1    = wsu;                    // overlays featT

  k0<<<dim3(4416), dim3(256), 0, stream>>>(feat, phi_w, theta_w, weight,
                                           featT, featV, wbp, wbt, weightT);
  k1_gemm<<<dim3(512), dim3(512), 0, stream>>>(featT, wbp, wbt, phi_n, theta_n);
  k3_attn<<<dim3(512), dim3(512), 0, stream>>>(phi_n, theta_n, featV, out1);
  k4_out<<<dim3(512), dim3(512), 0, stream>>>(out1, weightT, out);
}

// Round 11
// 503.486 us; speedup vs baseline: 1.8226x; 1.0535x over previous
//
#include <hip/hip_runtime.h>

// B=8, N=HW=4096, D=512, I=256, DO=512
// ws (ushort offsets):
//   featT  @0        [b][n=4096][c=512] bf16 (k0->k1)
//   featV  @16777216 [b][mt=64][c=512][m=64] bf16 (k0->k3)
//   phi_n  @33554432 [b][n][i=256] bf16 normalized (k1->k3)
//   theta_n@41943040 same (k1->k3)
//   wb_phi @50331648 [i=256][c=512] bf16 (k0->k1)
//   wb_th  @50462720
//   weightT@50593792 [d=512][c=512] bf16 (k0->k3 epilogue)
// end 50855936 ushorts = 101.7 MB (<= proven 134 MB)

typedef short s8v __attribute__((ext_vector_type(8)));
typedef float f4v __attribute__((ext_vector_type(4)));

__device__ inline ushort f2bf(float x) {
  union { float f; unsigned u; } v; v.f = x;
  unsigned u = v.u + 0x7fff + ((v.u >> 16) & 1);
  return (ushort)(u >> 16);
}

// ---------- k0 fused: all preprocessing in ONE launch ----------------------
// grid 4416 = [0,4096) k0a-body | [4096,4352) k0b-body | [4352,4416) k0c-body
__global__ __launch_bounds__(256) void k0(const float* __restrict__ feat,
                                          const float* __restrict__ pw,
                                          const float* __restrict__ tw,
                                          const float* __restrict__ w,
                                          ushort* __restrict__ featT,
                                          ushort* __restrict__ featV,
                                          ushort* __restrict__ wbp,
                                          ushort* __restrict__ wbt,
                                          ushort* __restrict__ wT) {
  int bid = blockIdx.x;
  int t = threadIdx.x;
  __shared__ ushort tile[64][72];

  if (bid < 4096) {
    // ---- k0a: feat fp32 [b][c][m] -> featV blocked bf16 + featT bf16 ----
    int b = bid >> 9, cb = (bid >> 6) & 7, mt = bid & 63;
#pragma unroll
    for (int p = 0; p < 4; p++) {
      int ci = p * 16 + (t >> 4);
      int mi = (t & 15) * 4;
      float4 v = *(const float4*)&feat[((size_t)(b * 512 + cb * 64 + ci)) * 4096 + mt * 64 + mi];
      ushort4 u; u.x = f2bf(v.x); u.y = f2bf(v.y); u.z = f2bf(v.z); u.w = f2bf(v.w);
      *(ushort4*)&featV[((size_t)(b * 64 + mt) * 512 + cb * 64 + ci) * 64 + mi] = u;
      tile[ci][mi] = u.x; tile[ci][mi + 1] = u.y; tile[ci][mi + 2] = u.z; tile[ci][mi + 3] = u.w;
    }
    __syncthreads();
    int m = t >> 2, cs = (t & 3) * 16;
    ushort tmp[16];
#pragma unroll
    for (int j = 0; j < 16; j++) tmp[j] = tile[cs + j][m];
    ushort* dst = &featT[((size_t)(b * 4096 + mt * 64 + m)) * 512 + cb * 64 + cs];
    *(s8v*)dst = *(s8v*)&tmp[0];
    *(s8v*)(dst + 8) = *(s8v*)&tmp[8];
  } else if (bid < 4352) {
    // ---- k0b: cast phi_w / theta_w -> bf16 ----
    int bb = bid - 4096;
    const float* src = (bb < 128) ? pw : tw;
    ushort* dst = (bb < 128) ? wbp : wbt;
    int idx = ((bb & 127) * 256 + t) * 4;
    float4 v = *(const float4*)&src[idx];
    ushort4 u; u.x = f2bf(v.x); u.y = f2bf(v.y); u.z = f2bf(v.z); u.w = f2bf(v.w);
    *(ushort4*)&dst[idx] = u;
  } else {
    // ---- k0c: weight fp32 [c][d] -> weightT bf16 [d][c] ----
    int bb = bid - 4352;
    int cb = bb >> 3, db = bb & 7;
#pragma unroll
    for (int p = 0; p < 4; p++) {
      int ci = p * 16 + (t >> 4);
      int di = (t & 15) * 4;
      float4 v = *(const float4*)&w[(size_t)(cb * 64 + ci) * 512 + db * 64 + di];
      tile[ci][di] = f2bf(v.x); tile[ci][di + 1] = f2bf(v.y);
      tile[ci][di + 2] = f2bf(v.z); tile[ci][di + 3] = f2bf(v.w);
    }
    __syncthreads();
    int d = t >> 2, cs = (t & 3) * 16;
    ushort tmp[16];
#pragma unroll
    for (int j = 0; j < 16; j++) tmp[j] = tile[cs + j][d];
    ushort* dst = &wT[(size_t)(db * 64 + d) * 512 + cb * 64 + cs];
    *(s8v*)dst = *(s8v*)&tmp[0];
    *(s8v*)(dst + 8) = *(s8v*)&tmp[8];
  }
}

// ---------- k1 v3: 64x64 wave tiles + cross-iter fragment pipeline ---------
// grid 512 = 8b(LSB) x 2half x 32nt, block 512 = 8 waves (wn=w>>2, wi=w&3).
__global__ __launch_bounds__(512) void k1_gemm(
    const ushort* __restrict__ featT, const ushort* __restrict__ wbp,
    const ushort* __restrict__ wbt, ushort* __restrict__ phi_n,
    ushort* __restrict__ theta_n) {
  int bid = blockIdx.x;
  int b = bid & 7;
  int rest = bid >> 3;
  int half = rest & 1;
  int nt = rest >> 1;
  const ushort* wb = half ? wbt : wbp;
  ushort* dst = half ? theta_n : phi_n;
  int t = threadIdx.x;
  int lane = t & 63, w = t >> 6;
  int col = lane & 15, quad = lane >> 4;
  int wn = w >> 2, wi = w & 3;
  int nb = nt * 128 + wn * 64;

  __shared__ float part[128][4];  // [n-local][wi] partial sum-of-squares

  const ushort* ab = featT + ((size_t)(b * 4096 + nb + col)) * 512 + quad * 8;
  const ushort* bb = wb + ((size_t)(wi * 64 + col)) * 512 + quad * 8;

  f4v acc[16];
#pragma unroll
  for (int i = 0; i < 16; i++) acc[i] = (f4v){0.f, 0.f, 0.f, 0.f};

  s8v afA[4], bfA[4], afB[4], bfB[4];
#pragma unroll
  for (int rs = 0; rs < 4; rs++) afA[rs] = *(const s8v*)(ab + (size_t)(rs * 16) * 512);
#pragma unroll
  for (int ct = 0; ct < 4; ct++) bfA[ct] = *(const s8v*)(bb + (size_t)(ct * 16) * 512);

#pragma unroll 1
  for (int kc = 0; kc < 16; kc += 2) {
#pragma unroll
    for (int rs = 0; rs < 4; rs++)
      afB[rs] = *(const s8v*)(ab + (size_t)(rs * 16) * 512 + (kc + 1) * 32);
#pragma unroll
    for (int ct = 0; ct < 4; ct++)
      bfB[ct] = *(const s8v*)(bb + (size_t)(ct * 16) * 512 + (kc + 1) * 32);
#pragma unroll
    for (int rs = 0; rs < 4; rs++)
#pragma unroll
      for (int ct = 0; ct < 4; ct++)
        acc[rs * 4 + ct] =
            __builtin_amdgcn_mfma_f32_16x16x32_bf16(afA[rs], bfA[ct], acc[rs * 4 + ct], 0, 0, 0);
    if (kc + 2 < 16) {
#pragma unroll
      for (int rs = 0; rs < 4; rs++)
        afA[rs] = *(const s8v*)(ab + (size_t)(rs * 16) * 512 + (kc + 2) * 32);
#pragma unroll
      for (int ct = 0; ct < 4; ct++)
        bfA[ct] = *(const s8v*)(bb + (size_t)(ct * 16) * 512 + (kc + 2) * 32);
    }
#pragma unroll
    for (int rs = 0; rs < 4; rs++)
#pragma unroll
      for (int ct = 0; ct < 4; ct++)
        acc[rs * 4 + ct] =
            __builtin_amdgcn_mfma_f32_16x16x32_bf16(afB[rs], bfB[ct], acc[rs * 4 + ct], 0, 0, 0);
  }

  // partial ss over this wave's 64 i, per output row (rs, reg)
#pragma unroll
  for (int rs = 0; rs < 4; rs++) {
#pragma unroll
    for (int reg = 0; reg < 4; reg++) {
      float ss = 0.f;
#pragma unroll
      for (int ct = 0; ct < 4; ct++) {
        float v = acc[rs * 4 + ct][reg];
        ss += v * v;
      }
      ss += __shfl_xor(ss, 1); ss += __shfl_xor(ss, 2);
      ss += __shfl_xor(ss, 4); ss += __shfl_xor(ss, 8);
      if (col == 0) part[wn * 64 + rs * 16 + quad * 4 + reg][wi] = ss;
    }
  }
  __syncthreads();

  float rinv[4][4];
#pragma unroll
  for (int rs = 0; rs < 4; rs++) {
#pragma unroll
    for (int reg = 0; reg < 4; reg++) {
      float4 p = *(const float4*)&part[wn * 64 + rs * 16 + quad * 4 + reg][0];
      rinv[rs][reg] = rsqrtf(p.x + p.y + p.z + p.w);
    }
  }

#pragma unroll
  for (int rs = 0; rs < 4; rs++) {
#pragma unroll
    for (int ct = 0; ct < 4; ct++) {
#pragma unroll
      for (int reg = 0; reg < 4; reg++) {
        dst[((size_t)(b * 4096 + nb + rs * 16 + quad * 4 + reg)) * 256 +
            wi * 64 + ct * 16 + col] = f2bf(acc[rs * 4 + ct][reg] * rinv[rs][reg]);
      }
    }
  }
}

// ---------- k3: flash attention + FUSED k4 epilogue ------------------------
// grid 512 = 8b(LSB) x 64qt, block 512 = 8 waves, 1 block/CU (LDS ~83KB).
// Main loop = R10 champion (relaxed lgkmcnt-only barrier, 4-way QK split).
// NEW: instead of writing out1 to global (+ separate k4 kernel), the
// normalized 64n x 512c tile goes into ks (dead after last QK; exactly 64KB,
// XOR-swizzled) and each wave runs the k4 GEMM for its 64-d range:
// out[b][d][n0+n] = relu(sum_c wT[d][c] * tile[n][c]). Deletes k4's launch,
// out1 32MB round-trip, and its boot; adds ~256 MFMA + 64KB wT L2 reads/wave.
__global__ __launch_bounds__(512, 2) void k3_attn(
    const ushort* __restrict__ phi_n, const ushort* __restrict__ theta_n,
    const ushort* __restrict__ featV, const ushort* __restrict__ wT,
    float* __restrict__ out) {
  int bid = blockIdx.x;
  int b = bid & 7;
  int n0 = (bid >> 3) << 6;
  int t = threadIdx.x;
  int lane = t & 63, w = t >> 6;
  int col = lane & 15, quad = lane >> 4;
  int mh4 = w & 3, rh = w >> 2;
  int l32 = lane & 31, h32 = lane >> 5;
  int cs = col & 7;

  __shared__ __align__(16) ushort ks[2 * 16384];  // [buf][row*256+(chunk^(row&7))*8]; reused as out1 tile
  __shared__ __align__(16) ushort ps[2 * 4096];   // [buf][n*64 + (chunk^(n&7))*8]
  __shared__ float dred[4 * 64];                  // [mh4][n]

  // Q A-frags, two 16-row sets: rows rh*32 + s*16 + col, k = f*32 + quad*8
  s8v qfA[8], qfB[8];
  {
    const ushort* qa = phi_n + ((size_t)(b * 4096 + n0 + rh * 32 + col)) * 256 + quad * 8;
#pragma unroll
    for (int f = 0; f < 8; f++) qfA[f] = *(const s8v*)(qa + f * 32);
    const ushort* qb = qa + 16 * 256;
#pragma unroll
    for (int f = 0; f < 8; f++) qfB[f] = *(const s8v*)(qb + f * 32);
  }

  const ushort* thb = theta_n + (size_t)b * 4096 * 256;
  const ushort* vbb = featV + (size_t)b * 64 * 512 * 64 + (size_t)(w * 64) * 64;

  f4v acc[16];
#pragma unroll
  for (int i = 0; i < 16; i++) acc[i] = (f4v){0.f, 0.f, 0.f, 0.f};
  float denp[8] = {0.f, 0.f, 0.f, 0.f, 0.f, 0.f, 0.f, 0.f};  // [set*4+r]

  // stage tile 0 into ks[0]
#pragma unroll
  for (int u = 0; u < 4; u++) {
    int row = w * 8 + u * 2 + h32;
    s8v val = *(const s8v*)(thb + (size_t)row * 256 + l32 * 8);
    *(s8v*)(ks + row * 256 + ((l32 ^ (row & 7)) * 8)) = val;
  }
  __syncthreads();

#pragma unroll 1
  for (int mt = 0; mt < 64; mt++) {
    const ushort* kc_ = ks + (mt & 1) * 16384;
    ushort* kn_ = ks + ((mt & 1) ^ 1) * 16384;
    ushort* pw_ = ps + (mt & 1) * 4096;

    // prefetch next K tile into regs (issued early, drained after exp)
    s8v kreg[4];
    if (mt < 63) {
      int m1 = (mt + 1) << 6;
#pragma unroll
      for (int u = 0; u < 4; u++) {
        int row = w * 8 + u * 2 + h32;
        kreg[u] = *(const s8v*)(thb + (size_t)(m1 + row) * 256 + l32 * 8);
      }
    }
    // V B-frags for this tile (consumed after the barrier; relaxed barrier
    // lets these stay in flight across it)
    s8v v0[4], v1[4];
    {
      const ushort* vb = vbb + (size_t)mt * 32768;
#pragma unroll
      for (int ct = 0; ct < 4; ct++) {
        const ushort* p = vb + (ct * 16 + col) * 64 + quad * 8;
        v0[ct] = *(const s8v*)p;
        v1[ct] = *(const s8v*)(p + 32);
      }
    }

    // QK: 4 independent chains of 4; each B-frag feeds both Q row-sets
    f4v svA0 = (f4v){0.f, 0.f, 0.f, 0.f}, svA1 = (f4v){0.f, 0.f, 0.f, 0.f};
    f4v svB0 = (f4v){0.f, 0.f, 0.f, 0.f}, svB1 = (f4v){0.f, 0.f, 0.f, 0.f};
    {
      const ushort* kb = kc_ + (mh4 * 16 + col) * 256;
      __builtin_amdgcn_s_setprio(1);
#pragma unroll
      for (int kk = 0; kk < 8; kk += 2) {
        int pos0 = ((kk * 4 + quad) ^ cs) * 8;
        int pos1 = (((kk + 1) * 4 + quad) ^ cs) * 8;
        s8v bf0 = *(const s8v*)(kb + pos0);
        s8v bf1 = *(const s8v*)(kb + pos1);
        svA0 = __builtin_amdgcn_mfma_f32_16x16x32_bf16(qfA[kk], bf0, svA0, 0, 0, 0);
        svB0 = __builtin_amdgcn_mfma_f32_16x16x32_bf16(qfB[kk], bf0, svB0, 0, 0, 0);
        svA1 = __builtin_amdgcn_mfma_f32_16x16x32_bf16(qfA[kk + 1], bf1, svA1, 0, 0, 0);
        svB1 = __builtin_amdgcn_mfma_f32_16x16x32_bf16(qfB[kk + 1], bf1, svB1, 0, 0, 0);
      }
      __builtin_amdgcn_s_setprio(0);
    }

    float pA[4], pB[4];
#pragma unroll
    for (int r = 0; r < 4; r++) {
      pA[r] = __expf(svA0[r] + svA1[r]);
      pB[r] = __expf(svB0[r] + svB1[r]);
      denp[r] += pA[r];
      denp[4 + r] += pB[r];
    }

    // P -> LDS (swizzled, double-buffered)
    {
      int j0 = mh4 * 2 + (col >> 3);
#pragma unroll
      for (int r = 0; r < 4; r++) {
        int nA = rh * 32 + quad * 4 + r;
        pw_[nA * 64 + ((j0 ^ (nA & 7)) * 8) + cs] = f2bf(pA[r]);
        int nB = nA + 16;
        pw_[nB * 64 + ((j0 ^ (nB & 7)) * 8) + cs] = f2bf(pB[r]);
      }
    }
    // write next K tile to other buffer
    if (mt < 63) {
#pragma unroll
      for (int u = 0; u < 4; u++) {
        int row = w * 8 + u * 2 + h32;
        *(s8v*)(kn_ + row * 256 + ((l32 ^ (row & 7)) * 8)) = kreg[u];
      }
    }
    // relaxed barrier: drain DS only; V loads remain in flight
    asm volatile("s_waitcnt lgkmcnt(0)" ::: "memory");
    __builtin_amdgcn_s_barrier();

    // PV: A = P (all 4 rowsets), B = v0/v1 (this wave's 64-c range)
    __builtin_amdgcn_s_setprio(1);
#pragma unroll
    for (int rs = 0; rs < 4; rs++) {
      const ushort* pb = pw_ + (rs * 16 + col) * 64;
      s8v pf0 = *(const s8v*)(pb + ((quad ^ cs) * 8));
      s8v pf1 = *(const s8v*)(pb + (((quad + 4) ^ cs) * 8));
#pragma unroll
      for (int ct = 0; ct < 4; ct++) {
        acc[rs * 4 + ct] =
            __builtin_amdgcn_mfma_f32_16x16x32_bf16(pf0, v0[ct], acc[rs * 4 + ct], 0, 0, 0);
        acc[rs * 4 + ct] =
            __builtin_amdgcn_mfma_f32_16x16x32_bf16(pf1, v1[ct], acc[rs * 4 + ct], 0, 0, 0);
      }
    }
    __builtin_amdgcn_s_setprio(0);
  }

  // denominator: reduce over 16-col group, then across the 4 mh4 waves
#pragma unroll
  for (int i = 0; i < 8; i++) {
    float d = denp[i];
    d += __shfl_xor(d, 1); d += __shfl_xor(d, 2);
    d += __shfl_xor(d, 4); d += __shfl_xor(d, 8);
    denp[i] = d;
  }
  if (col == 0) {
#pragma unroll
    for (int i = 0; i < 8; i++) {
      int n = rh * 32 + (i >> 2) * 16 + quad * 4 + (i & 3);
      dred[mh4 * 64 + n] = denp[i];
    }
  }
  __syncthreads();
  if (t < 64) dred[t] = 1.0f / (dred[t] + dred[64 + t] + dred[128 + t] + dred[192 + t]);
  __syncthreads();  // all waves past last ks read; dred final

  // ---- fused k4 epilogue ----
  // 1) normalized out1 tile (64n x 512c bf16) -> ks (XOR-swizzled per 8-chunk)
  //    elem (n, c) at ks[n*512 + ((c>>3 ^ (n&7))*8) + (c&7)]
#pragma unroll
  for (int rs = 0; rs < 4; rs++) {
#pragma unroll
    for (int ct = 0; ct < 4; ct++) {
      int c = w * 64 + ct * 16 + col;
      int chunk = c >> 3;
#pragma unroll
      for (int reg = 0; reg < 4; reg++) {
        int n = rs * 16 + quad * 4 + reg;
        ks[n * 512 + ((chunk ^ (n & 7)) * 8) + (c & 7)] =
            f2bf(acc[rs * 4 + ct][reg] * dred[n]);
      }
    }
  }
  __syncthreads();

  // 2) GEMM: out[b][d][n0+n] = relu(sum_c wT[d][c]*tile[n][c]); wave owns 64 d
  {
    const ushort* ab = wT + (size_t)(w * 64 + col) * 512 + quad * 8;
    f4v acc2[16];
#pragma unroll
    for (int i = 0; i < 16; i++) acc2[i] = (f4v){0.f, 0.f, 0.f, 0.f};
#pragma unroll 2
    for (int kc = 0; kc < 16; kc++) {
      s8v af[4], bf[4];
#pragma unroll
      for (int rs = 0; rs < 4; rs++)
        af[rs] = *(const s8v*)(ab + (size_t)(rs * 16) * 512 + kc * 32);
#pragma unroll
      for (int ct = 0; ct < 4; ct++) {
        int n = ct * 16 + col;  // n&7 == cs
        bf[ct] = *(const s8v*)(ks + n * 512 + (((kc * 4 + quad) ^ cs) * 8));
      }
#pragma unroll
      for (int rs = 0; rs < 4; rs++)
#pragma unroll
        for (int ct = 0; ct < 4; ct++)
          acc2[rs * 4 + ct] =
              __builtin_amdgcn_mfma_f32_16x16x32_bf16(af[rs], bf[ct], acc2[rs * 4 + ct], 0, 0, 0);
    }
#pragma unroll
    for (int rs = 0; rs < 4; rs++) {
#pragma unroll
      for (int ct = 0; ct < 4; ct++) {
#pragma unroll
        for (int reg = 0; reg < 4; reg++) {
          int d = w * 64 + rs * 16 + quad * 4 + reg;
          int n = n0 + ct * 16 + col;
          out[((size_t)(b * 512 + d)) * 4096 + n] = fmaxf(acc2[rs * 4 + ct][reg], 0.f);
        }
      }
    }
  }
}

extern "C" void kernel_launch(void* const* d_in, const int* in_sizes, int n_in,
                              void* d_out, int out_size, void* d_ws, size_t ws_size,
                              hipStream_t stream) {
  const float* feat    = (const float*)d_in[0];
  const float* phi_w   = (const float*)d_in[1];
  const float* theta_w = (const float*)d_in[2];
  const float* weight  = (const float*)d_in[3];
  float* out = (float*)d_out;

  ushort* wsu = (ushort*)d_ws;
  ushort* featT   = wsu;
  ushort* featV   = wsu + 16777216;
  ushort* phi_n   = wsu + 33554432;
  ushort* theta_n = wsu + 41943040;
  ushort* wbp     = wsu + 50331648;
  ushort* wbt     = wsu + 50462720;
  ushort* weightT = wsu + 50593792;

  k0<<<dim3(4416), dim3(256), 0, stream>>>(feat, phi_w, theta_w, weight,
                                           featT, featV, wbp, wbt, weightT);
  k1_gemm<<<dim3(512), dim3(512), 0, stream>>>(featT, wbp, wbt, phi_n, theta_n);
  k3_attn<<<dim3(512), dim3(512), 0, stream>>>(phi_n, theta_n, featV, weightT, out);
}

// Round 12
// 503.246 us; speedup vs baseline: 1.8234x; 1.0005x over previous
//
#include <hip/hip_runtime.h>

// B=8, N=HW=4096, D=512, I=256, DO=512
// ws (ushort offsets):
//   featT  @0        [b][n=4096][c=512] bf16 (k0->k1)
//   featV  @16777216 [b][mt=64][c=512][m=64] bf16 (k0->k3)
//   phi_n  @33554432 [b][n][i=256] bf16 normalized (k1->k3)
//   theta_n@41943040 same (k1->k3)
//   wb_phi @50331648 [i=256][c=512] bf16 (k0->k1)
//   wb_th  @50462720
//   weightT@50593792 [d=512][c=512] bf16 (k0->k3 epilogue)
// end 50855936 ushorts = 101.7 MB (<= proven 134 MB)

typedef short s8v __attribute__((ext_vector_type(8)));
typedef float f4v __attribute__((ext_vector_type(4)));

__device__ inline ushort f2bf(float x) {
  union { float f; unsigned u; } v; v.f = x;
  unsigned u = v.u + 0x7fff + ((v.u >> 16) & 1);
  return (ushort)(u >> 16);
}

// ---------- k0 fused: all preprocessing in ONE launch ----------------------
// grid 4416 = [0,4096) k0a-body | [4096,4352) k0b-body | [4352,4416) k0c-body
__global__ __launch_bounds__(256) void k0(const float* __restrict__ feat,
                                          const float* __restrict__ pw,
                                          const float* __restrict__ tw,
                                          const float* __restrict__ w,
                                          ushort* __restrict__ featT,
                                          ushort* __restrict__ featV,
                                          ushort* __restrict__ wbp,
                                          ushort* __restrict__ wbt,
                                          ushort* __restrict__ wT) {
  int bid = blockIdx.x;
  int t = threadIdx.x;
  __shared__ ushort tile[64][72];

  if (bid < 4096) {
    // ---- k0a: feat fp32 [b][c][m] -> featV blocked bf16 + featT bf16 ----
    int b = bid >> 9, cb = (bid >> 6) & 7, mt = bid & 63;
#pragma unroll
    for (int p = 0; p < 4; p++) {
      int ci = p * 16 + (t >> 4);
      int mi = (t & 15) * 4;
      float4 v = *(const float4*)&feat[((size_t)(b * 512 + cb * 64 + ci)) * 4096 + mt * 64 + mi];
      ushort4 u; u.x = f2bf(v.x); u.y = f2bf(v.y); u.z = f2bf(v.z); u.w = f2bf(v.w);
      *(ushort4*)&featV[((size_t)(b * 64 + mt) * 512 + cb * 64 + ci) * 64 + mi] = u;
      tile[ci][mi] = u.x; tile[ci][mi + 1] = u.y; tile[ci][mi + 2] = u.z; tile[ci][mi + 3] = u.w;
    }
    __syncthreads();
    int m = t >> 2, cs = (t & 3) * 16;
    ushort tmp[16];
#pragma unroll
    for (int j = 0; j < 16; j++) tmp[j] = tile[cs + j][m];
    ushort* dst = &featT[((size_t)(b * 4096 + mt * 64 + m)) * 512 + cb * 64 + cs];
    *(s8v*)dst = *(s8v*)&tmp[0];
    *(s8v*)(dst + 8) = *(s8v*)&tmp[8];
  } else if (bid < 4352) {
    // ---- k0b: cast phi_w / theta_w -> bf16 ----
    int bb = bid - 4096;
    const float* src = (bb < 128) ? pw : tw;
    ushort* dst = (bb < 128) ? wbp : wbt;
    int idx = ((bb & 127) * 256 + t) * 4;
    float4 v = *(const float4*)&src[idx];
    ushort4 u; u.x = f2bf(v.x); u.y = f2bf(v.y); u.z = f2bf(v.z); u.w = f2bf(v.w);
    *(ushort4*)&dst[idx] = u;
  } else {
    // ---- k0c: weight fp32 [c][d] -> weightT bf16 [d][c] ----
    int bb = bid - 4352;
    int cb = bb >> 3, db = bb & 7;
#pragma unroll
    for (int p = 0; p < 4; p++) {
      int ci = p * 16 + (t >> 4);
      int di = (t & 15) * 4;
      float4 v = *(const float4*)&w[(size_t)(cb * 64 + ci) * 512 + db * 64 + di];
      tile[ci][di] = f2bf(v.x); tile[ci][di + 1] = f2bf(v.y);
      tile[ci][di + 2] = f2bf(v.z); tile[ci][di + 3] = f2bf(v.w);
    }
    __syncthreads();
    int d = t >> 2, cs = (t & 3) * 16;
    ushort tmp[16];
#pragma unroll
    for (int j = 0; j < 16; j++) tmp[j] = tile[cs + j][d];
    ushort* dst = &wT[(size_t)(db * 64 + d) * 512 + cb * 64 + cs];
    *(s8v*)dst = *(s8v*)&tmp[0];
    *(s8v*)(dst + 8) = *(s8v*)&tmp[8];
  }
}

// ---------- k1 v4: 64x64 wave tiles, 128-combined-reg tier (4 waves/SIMD) --
// grid 512 = 8b(LSB) x 2half x 32nt, block 512 = 8 waves (wn=w>>2, wi=w&3).
// k1's live set genuinely fits the 128-combined tier (acc 64 AGPR + ~55 arch:
// frags 32 + addr/idx ~20) -- unlike k3 (184+, R2/R3 spill). __launch_bounds__
// (512,4) doubles occupancy 2->4 waves/SIMD to hide the L2 load latency that
// made k1 run at ~250 TF. Simple unroll-2 loop (R8 form) keeps arch VGPR <=64.
__global__ __launch_bounds__(512, 4) void k1_gemm(
    const ushort* __restrict__ featT, const ushort* __restrict__ wbp,
    const ushort* __restrict__ wbt, ushort* __restrict__ phi_n,
    ushort* __restrict__ theta_n) {
  int bid = blockIdx.x;
  int b = bid & 7;
  int rest = bid >> 3;
  int half = rest & 1;
  int nt = rest >> 1;
  const ushort* wb = half ? wbt : wbp;
  ushort* dst = half ? theta_n : phi_n;
  int t = threadIdx.x;
  int lane = t & 63, w = t >> 6;
  int col = lane & 15, quad = lane >> 4;
  int wn = w >> 2, wi = w & 3;
  int nb = nt * 128 + wn * 64;

  __shared__ float part[128][4];  // [n-local][wi] partial sum-of-squares

  const ushort* ab = featT + ((size_t)(b * 4096 + nb + col)) * 512 + quad * 8;
  const ushort* bb = wb + ((size_t)(wi * 64 + col)) * 512 + quad * 8;

  f4v acc[16];
#pragma unroll
  for (int i = 0; i < 16; i++) acc[i] = (f4v){0.f, 0.f, 0.f, 0.f};

#pragma unroll 2
  for (int kc = 0; kc < 16; kc++) {
    s8v af[4], bf[4];
#pragma unroll
    for (int rs = 0; rs < 4; rs++)
      af[rs] = *(const s8v*)(ab + (size_t)(rs * 16) * 512 + kc * 32);
#pragma unroll
    for (int ct = 0; ct < 4; ct++)
      bf[ct] = *(const s8v*)(bb + (size_t)(ct * 16) * 512 + kc * 32);
#pragma unroll
    for (int rs = 0; rs < 4; rs++)
#pragma unroll
      for (int ct = 0; ct < 4; ct++)
        acc[rs * 4 + ct] =
            __builtin_amdgcn_mfma_f32_16x16x32_bf16(af[rs], bf[ct], acc[rs * 4 + ct], 0, 0, 0);
  }

  // partial ss over this wave's 64 i, per output row (rs, reg)
#pragma unroll
  for (int rs = 0; rs < 4; rs++) {
#pragma unroll
    for (int reg = 0; reg < 4; reg++) {
      float ss = 0.f;
#pragma unroll
      for (int ct = 0; ct < 4; ct++) {
        float v = acc[rs * 4 + ct][reg];
        ss += v * v;
      }
      ss += __shfl_xor(ss, 1); ss += __shfl_xor(ss, 2);
      ss += __shfl_xor(ss, 4); ss += __shfl_xor(ss, 8);
      if (col == 0) part[wn * 64 + rs * 16 + quad * 4 + reg][wi] = ss;
    }
  }
  __syncthreads();

  float rinv[4][4];
#pragma unroll
  for (int rs = 0; rs < 4; rs++) {
#pragma unroll
    for (int reg = 0; reg < 4; reg++) {
      float4 p = *(const float4*)&part[wn * 64 + rs * 16 + quad * 4 + reg][0];
      rinv[rs][reg] = rsqrtf(p.x + p.y + p.z + p.w);
    }
  }

#pragma unroll
  for (int rs = 0; rs < 4; rs++) {
#pragma unroll
    for (int ct = 0; ct < 4; ct++) {
#pragma unroll
      for (int reg = 0; reg < 4; reg++) {
        dst[((size_t)(b * 4096 + nb + rs * 16 + quad * 4 + reg)) * 256 +
            wi * 64 + ct * 16 + col] = f2bf(acc[rs * 4 + ct][reg] * rinv[rs][reg]);
      }
    }
  }
}

// ---------- k3: flash attention + FUSED k4 epilogue (R11 champion, verbatim)
// grid 512 = 8b(LSB) x 64qt, block 512 = 8 waves, 1 block/CU (LDS ~83KB).
// Main loop: relaxed lgkmcnt-only barrier, 4-way QK split, K/P dbuf.
// Epilogue: normalized 64n x 512c tile -> ks (XOR-swizzled), per-wave 64-d
// GEMM vs weightT, relu, direct fp32 store. 350.5us measured, no spill.
__global__ __launch_bounds__(512, 2) void k3_attn(
    const ushort* __restrict__ phi_n, const ushort* __restrict__ theta_n,
    const ushort* __restrict__ featV, const ushort* __restrict__ wT,
    float* __restrict__ out) {
  int bid = blockIdx.x;
  int b = bid & 7;
  int n0 = (bid >> 3) << 6;
  int t = threadIdx.x;
  int lane = t & 63, w = t >> 6;
  int col = lane & 15, quad = lane >> 4;
  int mh4 = w & 3, rh = w >> 2;
  int l32 = lane & 31, h32 = lane >> 5;
  int cs = col & 7;

  __shared__ __align__(16) ushort ks[2 * 16384];  // [buf][row*256+(chunk^(row&7))*8]; reused as out1 tile
  __shared__ __align__(16) ushort ps[2 * 4096];   // [buf][n*64 + (chunk^(n&7))*8]
  __shared__ float dred[4 * 64];                  // [mh4][n]

  // Q A-frags, two 16-row sets: rows rh*32 + s*16 + col, k = f*32 + quad*8
  s8v qfA[8], qfB[8];
  {
    const ushort* qa = phi_n + ((size_t)(b * 4096 + n0 + rh * 32 + col)) * 256 + quad * 8;
#pragma unroll
    for (int f = 0; f < 8; f++) qfA[f] = *(const s8v*)(qa + f * 32);
    const ushort* qb = qa + 16 * 256;
#pragma unroll
    for (int f = 0; f < 8; f++) qfB[f] = *(const s8v*)(qb + f * 32);
  }

  const ushort* thb = theta_n + (size_t)b * 4096 * 256;
  const ushort* vbb = featV + (size_t)b * 64 * 512 * 64 + (size_t)(w * 64) * 64;

  f4v acc[16];
#pragma unroll
  for (int i = 0; i < 16; i++) acc[i] = (f4v){0.f, 0.f, 0.f, 0.f};
  float denp[8] = {0.f, 0.f, 0.f, 0.f, 0.f, 0.f, 0.f, 0.f};  // [set*4+r]

  // stage tile 0 into ks[0]
#pragma unroll
  for (int u = 0; u < 4; u++) {
    int row = w * 8 + u * 2 + h32;
    s8v val = *(const s8v*)(thb + (size_t)row * 256 + l32 * 8);
    *(s8v*)(ks + row * 256 + ((l32 ^ (row & 7)) * 8)) = val;
  }
  __syncthreads();

#pragma unroll 1
  for (int mt = 0; mt < 64; mt++) {
    const ushort* kc_ = ks + (mt & 1) * 16384;
    ushort* kn_ = ks + ((mt & 1) ^ 1) * 16384;
    ushort* pw_ = ps + (mt & 1) * 4096;

    // prefetch next K tile into regs (issued early, drained after exp)
    s8v kreg[4];
    if (mt < 63) {
      int m1 = (mt + 1) << 6;
#pragma unroll
      for (int u = 0; u < 4; u++) {
        int row = w * 8 + u * 2 + h32;
        kreg[u] = *(const s8v*)(thb + (size_t)(m1 + row) * 256 + l32 * 8);
      }
    }
    // V B-frags for this tile (consumed after the barrier; relaxed barrier
    // lets these stay in flight across it)
    s8v v0[4], v1[4];
    {
      const ushort* vb = vbb + (size_t)mt * 32768;
#pragma unroll
      for (int ct = 0; ct < 4; ct++) {
        const ushort* p = vb + (ct * 16 + col) * 64 + quad * 8;
        v0[ct] = *(const s8v*)p;
        v1[ct] = *(const s8v*)(p + 32);
      }
    }

    // QK: 4 independent chains of 4; each B-frag feeds both Q row-sets
    f4v svA0 = (f4v){0.f, 0.f, 0.f, 0.f}, svA1 = (f4v){0.f, 0.f, 0.f, 0.f};
    f4v svB0 = (f4v){0.f, 0.f, 0.f, 0.f}, svB1 = (f4v){0.f, 0.f, 0.f, 0.f};
    {
      const ushort* kb = kc_ + (mh4 * 16 + col) * 256;
      __builtin_amdgcn_s_setprio(1);
#pragma unroll
      for (int kk = 0; kk < 8; kk += 2) {
        int pos0 = ((kk * 4 + quad) ^ cs) * 8;
        int pos1 = (((kk + 1) * 4 + quad) ^ cs) * 8;
        s8v bf0 = *(const s8v*)(kb + pos0);
        s8v bf1 = *(const s8v*)(kb + pos1);
        svA0 = __builtin_amdgcn_mfma_f32_16x16x32_bf16(qfA[kk], bf0, svA0, 0, 0, 0);
        svB0 = __builtin_amdgcn_mfma_f32_16x16x32_bf16(qfB[kk], bf0, svB0, 0, 0, 0);
        svA1 = __builtin_amdgcn_mfma_f32_16x16x32_bf16(qfA[kk + 1], bf1, svA1, 0, 0, 0);
        svB1 = __builtin_amdgcn_mfma_f32_16x16x32_bf16(qfB[kk + 1], bf1, svB1, 0, 0, 0);
      }
      __builtin_amdgcn_s_setprio(0);
    }

    float pA[4], pB[4];
#pragma unroll
    for (int r = 0; r < 4; r++) {
      pA[r] = __expf(svA0[r] + svA1[r]);
      pB[r] = __expf(svB0[r] + svB1[r]);
      denp[r] += pA[r];
      denp[4 + r] += pB[r];
    }

    // P -> LDS (swizzled, double-buffered)
    {
      int j0 = mh4 * 2 + (col >> 3);
#pragma unroll
      for (int r = 0; r < 4; r++) {
        int nA = rh * 32 + quad * 4 + r;
        pw_[nA * 64 + ((j0 ^ (nA & 7)) * 8) + cs] = f2bf(pA[r]);
        int nB = nA + 16;
        pw_[nB * 64 + ((j0 ^ (nB & 7)) * 8) + cs] = f2bf(pB[r]);
      }
    }
    // write next K tile to other buffer
    if (mt < 63) {
#pragma unroll
      for (int u = 0; u < 4; u++) {
        int row = w * 8 + u * 2 + h32;
        *(s8v*)(kn_ + row * 256 + ((l32 ^ (row & 7)) * 8)) = kreg[u];
      }
    }
    // relaxed barrier: drain DS only; V loads remain in flight
    asm volatile("s_waitcnt lgkmcnt(0)" ::: "memory");
    __builtin_amdgcn_s_barrier();

    // PV: A = P (all 4 rowsets), B = v0/v1 (this wave's 64-c range)
    __builtin_amdgcn_s_setprio(1);
#pragma unroll
    for (int rs = 0; rs < 4; rs++) {
      const ushort* pb = pw_ + (rs * 16 + col) * 64;
      s8v pf0 = *(const s8v*)(pb + ((quad ^ cs) * 8));
      s8v pf1 = *(const s8v*)(pb + (((quad + 4) ^ cs) * 8));
#pragma unroll
      for (int ct = 0; ct < 4; ct++) {
        acc[rs * 4 + ct] =
            __builtin_amdgcn_mfma_f32_16x16x32_bf16(pf0, v0[ct], acc[rs * 4 + ct], 0, 0, 0);
        acc[rs * 4 + ct] =
            __builtin_amdgcn_mfma_f32_16x16x32_bf16(pf1, v1[ct], acc[rs * 4 + ct], 0, 0, 0);
      }
    }
    __builtin_amdgcn_s_setprio(0);
  }

  // denominator: reduce over 16-col group, then across the 4 mh4 waves
#pragma unroll
  for (int i = 0; i < 8; i++) {
    float d = denp[i];
    d += __shfl_xor(d, 1); d += __shfl_xor(d, 2);
    d += __shfl_xor(d, 4); d += __shfl_xor(d, 8);
    denp[i] = d;
  }
  if (col == 0) {
#pragma unroll
    for (int i = 0; i < 8; i++) {
      int n = rh * 32 + (i >> 2) * 16 + quad * 4 + (i & 3);
      dred[mh4 * 64 + n] = denp[i];
    }
  }
  __syncthreads();
  if (t < 64) dred[t] = 1.0f / (dred[t] + dred[64 + t] + dred[128 + t] + dred[192 + t]);
  __syncthreads();  // all waves past last ks read; dred final

  // ---- fused k4 epilogue ----
  // 1) normalized out1 tile (64n x 512c bf16) -> ks (XOR-swizzled per 8-chunk)
  //    elem (n, c) at ks[n*512 + ((c>>3 ^ (n&7))*8) + (c&7)]
#pragma unroll
  for (int rs = 0; rs < 4; rs++) {
#pragma unroll
    for (int ct = 0; ct < 4; ct++) {
      int c = w * 64 + ct * 16 + col;
      int chunk = c >> 3;
#pragma unroll
      for (int reg = 0; reg < 4; reg++) {
        int n = rs * 16 + quad * 4 + reg;
        ks[n * 512 + ((chunk ^ (n & 7)) * 8) + (c & 7)] =
            f2bf(acc[rs * 4 + ct][reg] * dred[n]);
      }
    }
  }
  __syncthreads();

  // 2) GEMM: out[b][d][n0+n] = relu(sum_c wT[d][c]*tile[n][c]); wave owns 64 d
  {
    const ushort* ab = wT + (size_t)(w * 64 + col) * 512 + quad * 8;
    f4v acc2[16];
#pragma unroll
    for (int i = 0; i < 16; i++) acc2[i] = (f4v){0.f, 0.f, 0.f, 0.f};
#pragma unroll 2
    for (int kc = 0; kc < 16; kc++) {
      s8v af[4], bf[4];
#pragma unroll
      for (int rs = 0; rs < 4; rs++)
        af[rs] = *(const s8v*)(ab + (size_t)(rs * 16) * 512 + kc * 32);
#pragma unroll
      for (int ct = 0; ct < 4; ct++) {
        int n = ct * 16 + col;  // n&7 == cs
        bf[ct] = *(const s8v*)(ks + n * 512 + (((kc * 4 + quad) ^ cs) * 8));
      }
#pragma unroll
      for (int rs = 0; rs < 4; rs++)
#pragma unroll
        for (int ct = 0; ct < 4; ct++)
          acc2[rs * 4 + ct] =
              __builtin_amdgcn_mfma_f32_16x16x32_bf16(af[rs], bf[ct], acc2[rs * 4 + ct], 0, 0, 0);
    }
#pragma unroll
    for (int rs = 0; rs < 4; rs++) {
#pragma unroll
      for (int ct = 0; ct < 4; ct++) {
#pragma unroll
        for (int reg = 0; reg < 4; reg++) {
          int d = w * 64 + rs * 16 + quad * 4 + reg;
          int n = n0 + ct * 16 + col;
          out[((size_t)(b * 512 + d)) * 4096 + n] = fmaxf(acc2[rs * 4 + ct][reg], 0.f);
        }
      }
    }
  }
}

extern "C" void kernel_launch(void* const* d_in, const int* in_sizes, int n_in,
                              void* d_out, int out_size, void* d_ws, size_t ws_size,
                              hipStream_t stream) {
  const float* feat    = (const float*)d_in[0];
  const float* phi_w   = (const float*)d_in[1];
  const float* theta_w = (const float*)d_in[2];
  const float* weight  = (const float*)d_in[3];
  float* out = (float*)d_out;

  ushort* wsu = (ushort*)d_ws;
  ushort* featT   = wsu;
  ushort* featV   = wsu + 16777216;
  ushort* phi_n   = wsu + 33554432;
  ushort* theta_n = wsu + 41943040;
  ushort* wbp     = wsu + 50331648;
  ushort* wbt     = wsu + 50462720;
  ushort* weightT = wsu + 50593792;

  k0<<<dim3(4416), dim3(256), 0, stream>>>(feat, phi_w, theta_w, weight,
                                           featT, featV, wbp, wbt, weightT);
  k1_gemm<<<dim3(512), dim3(512), 0, stream>>>(featT, wbp, wbt, phi_n, theta_n);
  k3_attn<<<dim3(512), dim3(512), 0, stream>>>(phi_n, theta_n, featV, weightT, out);
}

// Round 13
// 494.213 us; speedup vs baseline: 1.8567x; 1.0183x over previous
//
#include <hip/hip_runtime.h>

// B=8, N=HW=4096, D=512, I=256, DO=512
// ws (ushort offsets):
//   featT  @0        [b][n=4096][c=512] bf16 (k0->k1)
//   featV  @16777216 [b][mt=64][c=512][m=64] bf16 (k0->k3)
//   phi_n  @33554432 [b][n][i=256] bf16 normalized (k1->k3)
//   theta_n@41943040 same (k1->k3)
//   wb_phi @50331648 [i=256][c=512] bf16 (k0->k1)
//   wb_th  @50462720
//   weightT@50593792 [d=512][c=512] bf16 (k0->k3 epilogue)
// end 50855936 ushorts = 101.7 MB (<= proven 134 MB)

typedef short s8v __attribute__((ext_vector_type(8)));
typedef float f4v __attribute__((ext_vector_type(4)));

__device__ inline ushort f2bf(float x) {
  union { float f; unsigned u; } v; v.f = x;
  unsigned u = v.u + 0x7fff + ((v.u >> 16) & 1);
  return (ushort)(u >> 16);
}

// ---------- k0 fused: all preprocessing in ONE launch ----------------------
// grid 4416 = [0,4096) k0a-body | [4096,4352) k0b-body | [4352,4416) k0c-body
__global__ __launch_bounds__(256) void k0(const float* __restrict__ feat,
                                          const float* __restrict__ pw,
                                          const float* __restrict__ tw,
                                          const float* __restrict__ w,
                                          ushort* __restrict__ featT,
                                          ushort* __restrict__ featV,
                                          ushort* __restrict__ wbp,
                                          ushort* __restrict__ wbt,
                                          ushort* __restrict__ wT) {
  int bid = blockIdx.x;
  int t = threadIdx.x;
  __shared__ ushort tile[64][72];

  if (bid < 4096) {
    // ---- k0a: feat fp32 [b][c][m] -> featV blocked bf16 + featT bf16 ----
    int b = bid >> 9, cb = (bid >> 6) & 7, mt = bid & 63;
#pragma unroll
    for (int p = 0; p < 4; p++) {
      int ci = p * 16 + (t >> 4);
      int mi = (t & 15) * 4;
      float4 v = *(const float4*)&feat[((size_t)(b * 512 + cb * 64 + ci)) * 4096 + mt * 64 + mi];
      ushort4 u; u.x = f2bf(v.x); u.y = f2bf(v.y); u.z = f2bf(v.z); u.w = f2bf(v.w);
      *(ushort4*)&featV[((size_t)(b * 64 + mt) * 512 + cb * 64 + ci) * 64 + mi] = u;
      tile[ci][mi] = u.x; tile[ci][mi + 1] = u.y; tile[ci][mi + 2] = u.z; tile[ci][mi + 3] = u.w;
    }
    __syncthreads();
    int m = t >> 2, cs = (t & 3) * 16;
    ushort tmp[16];
#pragma unroll
    for (int j = 0; j < 16; j++) tmp[j] = tile[cs + j][m];
    ushort* dst = &featT[((size_t)(b * 4096 + mt * 64 + m)) * 512 + cb * 64 + cs];
    *(s8v*)dst = *(s8v*)&tmp[0];
    *(s8v*)(dst + 8) = *(s8v*)&tmp[8];
  } else if (bid < 4352) {
    // ---- k0b: cast phi_w / theta_w -> bf16 ----
    int bb = bid - 4096;
    const float* src = (bb < 128) ? pw : tw;
    ushort* dst = (bb < 128) ? wbp : wbt;
    int idx = ((bb & 127) * 256 + t) * 4;
    float4 v = *(const float4*)&src[idx];
    ushort4 u; u.x = f2bf(v.x); u.y = f2bf(v.y); u.z = f2bf(v.z); u.w = f2bf(v.w);
    *(ushort4*)&dst[idx] = u;
  } else {
    // ---- k0c: weight fp32 [c][d] -> weightT bf16 [d][c] ----
    int bb = bid - 4352;
    int cb = bb >> 3, db = bb & 7;
#pragma unroll
    for (int p = 0; p < 4; p++) {
      int ci = p * 16 + (t >> 4);
      int di = (t & 15) * 4;
      float4 v = *(const float4*)&w[(size_t)(cb * 64 + ci) * 512 + db * 64 + di];
      tile[ci][di] = f2bf(v.x); tile[ci][di + 1] = f2bf(v.y);
      tile[ci][di + 2] = f2bf(v.z); tile[ci][di + 3] = f2bf(v.w);
    }
    __syncthreads();
    int d = t >> 2, cs = (t & 3) * 16;
    ushort tmp[16];
#pragma unroll
    for (int j = 0; j < 16; j++) tmp[j] = tile[cs + j][d];
    ushort* dst = &wT[(size_t)(db * 64 + d) * 512 + cb * 64 + cs];
    *(s8v*)dst = *(s8v*)&tmp[0];
    *(s8v*)(dst + 8) = *(s8v*)&tmp[8];
  }
}

// ---------- k1 v4: 64x64 wave tiles, 128-combined-reg tier (4 waves/SIMD) --
// grid 512 = 8b(LSB) x 2half x 32nt, block 512 = 8 waves (wn=w>>2, wi=w&3).
__global__ __launch_bounds__(512, 4) void k1_gemm(
    const ushort* __restrict__ featT, const ushort* __restrict__ wbp,
    const ushort* __restrict__ wbt, ushort* __restrict__ phi_n,
    ushort* __restrict__ theta_n) {
  int bid = blockIdx.x;
  int b = bid & 7;
  int rest = bid >> 3;
  int half = rest & 1;
  int nt = rest >> 1;
  const ushort* wb = half ? wbt : wbp;
  ushort* dst = half ? theta_n : phi_n;
  int t = threadIdx.x;
  int lane = t & 63, w = t >> 6;
  int col = lane & 15, quad = lane >> 4;
  int wn = w >> 2, wi = w & 3;
  int nb = nt * 128 + wn * 64;

  __shared__ float part[128][4];  // [n-local][wi] partial sum-of-squares

  const ushort* ab = featT + ((size_t)(b * 4096 + nb + col)) * 512 + quad * 8;
  const ushort* bb = wb + ((size_t)(wi * 64 + col)) * 512 + quad * 8;

  f4v acc[16];
#pragma unroll
  for (int i = 0; i < 16; i++) acc[i] = (f4v){0.f, 0.f, 0.f, 0.f};

#pragma unroll 2
  for (int kc = 0; kc < 16; kc++) {
    s8v af[4], bf[4];
#pragma unroll
    for (int rs = 0; rs < 4; rs++)
      af[rs] = *(const s8v*)(ab + (size_t)(rs * 16) * 512 + kc * 32);
#pragma unroll
    for (int ct = 0; ct < 4; ct++)
      bf[ct] = *(const s8v*)(bb + (size_t)(ct * 16) * 512 + kc * 32);
#pragma unroll
    for (int rs = 0; rs < 4; rs++)
#pragma unroll
      for (int ct = 0; ct < 4; ct++)
        acc[rs * 4 + ct] =
            __builtin_amdgcn_mfma_f32_16x16x32_bf16(af[rs], bf[ct], acc[rs * 4 + ct], 0, 0, 0);
  }

  // partial ss over this wave's 64 i, per output row (rs, reg)
#pragma unroll
  for (int rs = 0; rs < 4; rs++) {
#pragma unroll
    for (int reg = 0; reg < 4; reg++) {
      float ss = 0.f;
#pragma unroll
      for (int ct = 0; ct < 4; ct++) {
        float v = acc[rs * 4 + ct][reg];
        ss += v * v;
      }
      ss += __shfl_xor(ss, 1); ss += __shfl_xor(ss, 2);
      ss += __shfl_xor(ss, 4); ss += __shfl_xor(ss, 8);
      if (col == 0) part[wn * 64 + rs * 16 + quad * 4 + reg][wi] = ss;
    }
  }
  __syncthreads();

  float rinv[4][4];
#pragma unroll
  for (int rs = 0; rs < 4; rs++) {
#pragma unroll
    for (int reg = 0; reg < 4; reg++) {
      float4 p = *(const float4*)&part[wn * 64 + rs * 16 + quad * 4 + reg][0];
      rinv[rs][reg] = rsqrtf(p.x + p.y + p.z + p.w);
    }
  }

#pragma unroll
  for (int rs = 0; rs < 4; rs++) {
#pragma unroll
    for (int ct = 0; ct < 4; ct++) {
#pragma unroll
      for (int reg = 0; reg < 4; reg++) {
        dst[((size_t)(b * 4096 + nb + rs * 16 + quad * 4 + reg)) * 256 +
            wi * 64 + ct * 16 + col] = f2bf(acc[rs * 4 + ct][reg] * rinv[rs][reg]);
      }
    }
  }
}

// ---------- k3: flash attention + fused k4 epilogue (v2: pipelined wT) -----
// grid 512 = 8b(LSB) x 64qt, block 512 = 8 waves, 1 block/CU (LDS ~83KB).
// Main loop: R11 champion verbatim (relaxed lgkmcnt barrier, 4-way QK split).
// Epilogue v2: the wT fragment loads were latency-exposed (64 x 1KB L2 loads
// interleaved with consuming MFMAs at 2 waves/SIMD -> ~44us for ~10us of
// work). Now: kc=0 loads issued BEFORE the dred/tile barriers (~600+cyc
// early), and the GEMM ping-pongs afA/afB one kc ahead (+16 VGPR, ~144 arch
// + 64 AGPR <= 256 tier). setprio(1) around epilogue MFMA cluster.
__global__ __launch_bounds__(512, 2) void k3_attn(
    const ushort* __restrict__ phi_n, const ushort* __restrict__ theta_n,
    const ushort* __restrict__ featV, const ushort* __restrict__ wT,
    float* __restrict__ out) {
  int bid = blockIdx.x;
  int b = bid & 7;
  int n0 = (bid >> 3) << 6;
  int t = threadIdx.x;
  int lane = t & 63, w = t >> 6;
  int col = lane & 15, quad = lane >> 4;
  int mh4 = w & 3, rh = w >> 2;
  int l32 = lane & 31, h32 = lane >> 5;
  int cs = col & 7;

  __shared__ __align__(16) ushort ks[2 * 16384];  // [buf][row*256+(chunk^(row&7))*8]; reused as out1 tile
  __shared__ __align__(16) ushort ps[2 * 4096];   // [buf][n*64 + (chunk^(n&7))*8]
  __shared__ float dred[4 * 64];                  // [mh4][n]

  // Q A-frags, two 16-row sets: rows rh*32 + s*16 + col, k = f*32 + quad*8
  s8v qfA[8], qfB[8];
  {
    const ushort* qa = phi_n + ((size_t)(b * 4096 + n0 + rh * 32 + col)) * 256 + quad * 8;
#pragma unroll
    for (int f = 0; f < 8; f++) qfA[f] = *(const s8v*)(qa + f * 32);
    const ushort* qb = qa + 16 * 256;
#pragma unroll
    for (int f = 0; f < 8; f++) qfB[f] = *(const s8v*)(qb + f * 32);
  }

  const ushort* thb = theta_n + (size_t)b * 4096 * 256;
  const ushort* vbb = featV + (size_t)b * 64 * 512 * 64 + (size_t)(w * 64) * 64;

  f4v acc[16];
#pragma unroll
  for (int i = 0; i < 16; i++) acc[i] = (f4v){0.f, 0.f, 0.f, 0.f};
  float denp[8] = {0.f, 0.f, 0.f, 0.f, 0.f, 0.f, 0.f, 0.f};  // [set*4+r]

  // stage tile 0 into ks[0]
#pragma unroll
  for (int u = 0; u < 4; u++) {
    int row = w * 8 + u * 2 + h32;
    s8v val = *(const s8v*)(thb + (size_t)row * 256 + l32 * 8);
    *(s8v*)(ks + row * 256 + ((l32 ^ (row & 7)) * 8)) = val;
  }
  __syncthreads();

#pragma unroll 1
  for (int mt = 0; mt < 64; mt++) {
    const ushort* kc_ = ks + (mt & 1) * 16384;
    ushort* kn_ = ks + ((mt & 1) ^ 1) * 16384;
    ushort* pw_ = ps + (mt & 1) * 4096;

    // prefetch next K tile into regs (issued early, drained after exp)
    s8v kreg[4];
    if (mt < 63) {
      int m1 = (mt + 1) << 6;
#pragma unroll
      for (int u = 0; u < 4; u++) {
        int row = w * 8 + u * 2 + h32;
        kreg[u] = *(const s8v*)(thb + (size_t)(m1 + row) * 256 + l32 * 8);
      }
    }
    // V B-frags for this tile (consumed after the barrier; relaxed barrier
    // lets these stay in flight across it)
    s8v v0[4], v1[4];
    {
      const ushort* vb = vbb + (size_t)mt * 32768;
#pragma unroll
      for (int ct = 0; ct < 4; ct++) {
        const ushort* p = vb + (ct * 16 + col) * 64 + quad * 8;
        v0[ct] = *(const s8v*)p;
        v1[ct] = *(const s8v*)(p + 32);
      }
    }

    // QK: 4 independent chains of 4; each B-frag feeds both Q row-sets
    f4v svA0 = (f4v){0.f, 0.f, 0.f, 0.f}, svA1 = (f4v){0.f, 0.f, 0.f, 0.f};
    f4v svB0 = (f4v){0.f, 0.f, 0.f, 0.f}, svB1 = (f4v){0.f, 0.f, 0.f, 0.f};
    {
      const ushort* kb = kc_ + (mh4 * 16 + col) * 256;
      __builtin_amdgcn_s_setprio(1);
#pragma unroll
      for (int kk = 0; kk < 8; kk += 2) {
        int pos0 = ((kk * 4 + quad) ^ cs) * 8;
        int pos1 = (((kk + 1) * 4 + quad) ^ cs) * 8;
        s8v bf0 = *(const s8v*)(kb + pos0);
        s8v bf1 = *(const s8v*)(kb + pos1);
        svA0 = __builtin_amdgcn_mfma_f32_16x16x32_bf16(qfA[kk], bf0, svA0, 0, 0, 0);
        svB0 = __builtin_amdgcn_mfma_f32_16x16x32_bf16(qfB[kk], bf0, svB0, 0, 0, 0);
        svA1 = __builtin_amdgcn_mfma_f32_16x16x32_bf16(qfA[kk + 1], bf1, svA1, 0, 0, 0);
        svB1 = __builtin_amdgcn_mfma_f32_16x16x32_bf16(qfB[kk + 1], bf1, svB1, 0, 0, 0);
      }
      __builtin_amdgcn_s_setprio(0);
    }

    float pA[4], pB[4];
#pragma unroll
    for (int r = 0; r < 4; r++) {
      pA[r] = __expf(svA0[r] + svA1[r]);
      pB[r] = __expf(svB0[r] + svB1[r]);
      denp[r] += pA[r];
      denp[4 + r] += pB[r];
    }

    // P -> LDS (swizzled, double-buffered)
    {
      int j0 = mh4 * 2 + (col >> 3);
#pragma unroll
      for (int r = 0; r < 4; r++) {
        int nA = rh * 32 + quad * 4 + r;
        pw_[nA * 64 + ((j0 ^ (nA & 7)) * 8) + cs] = f2bf(pA[r]);
        int nB = nA + 16;
        pw_[nB * 64 + ((j0 ^ (nB & 7)) * 8) + cs] = f2bf(pB[r]);
      }
    }
    // write next K tile to other buffer
    if (mt < 63) {
#pragma unroll
      for (int u = 0; u < 4; u++) {
        int row = w * 8 + u * 2 + h32;
        *(s8v*)(kn_ + row * 256 + ((l32 ^ (row & 7)) * 8)) = kreg[u];
      }
    }
    // relaxed barrier: drain DS only; V loads remain in flight
    asm volatile("s_waitcnt lgkmcnt(0)" ::: "memory");
    __builtin_amdgcn_s_barrier();

    // PV: A = P (all 4 rowsets), B = v0/v1 (this wave's 64-c range)
    __builtin_amdgcn_s_setprio(1);
#pragma unroll
    for (int rs = 0; rs < 4; rs++) {
      const ushort* pb = pw_ + (rs * 16 + col) * 64;
      s8v pf0 = *(const s8v*)(pb + ((quad ^ cs) * 8));
      s8v pf1 = *(const s8v*)(pb + (((quad + 4) ^ cs) * 8));
#pragma unroll
      for (int ct = 0; ct < 4; ct++) {
        acc[rs * 4 + ct] =
            __builtin_amdgcn_mfma_f32_16x16x32_bf16(pf0, v0[ct], acc[rs * 4 + ct], 0, 0, 0);
        acc[rs * 4 + ct] =
            __builtin_amdgcn_mfma_f32_16x16x32_bf16(pf1, v1[ct], acc[rs * 4 + ct], 0, 0, 0);
      }
    }
    __builtin_amdgcn_s_setprio(0);
  }

  // denominator: reduce over 16-col group, then across the 4 mh4 waves
#pragma unroll
  for (int i = 0; i < 8; i++) {
    float d = denp[i];
    d += __shfl_xor(d, 1); d += __shfl_xor(d, 2);
    d += __shfl_xor(d, 4); d += __shfl_xor(d, 8);
    denp[i] = d;
  }

  // early-issue epilogue wT loads for kc=0 (depend on nothing local; land
  // while the dred barriers + tile write execute)
  const ushort* ab = wT + (size_t)(w * 64 + col) * 512 + quad * 8;
  s8v afA[4], afB[4];
#pragma unroll
  for (int rs = 0; rs < 4; rs++)
    afA[rs] = *(const s8v*)(ab + (size_t)(rs * 16) * 512);

  if (col == 0) {
#pragma unroll
    for (int i = 0; i < 8; i++) {
      int n = rh * 32 + (i >> 2) * 16 + quad * 4 + (i & 3);
      dred[mh4 * 64 + n] = denp[i];
    }
  }
  __syncthreads();
  if (t < 64) dred[t] = 1.0f / (dred[t] + dred[64 + t] + dred[128 + t] + dred[192 + t]);
  __syncthreads();  // all waves past last ks read; dred final

  // ---- fused k4 epilogue ----
  // 1) normalized out1 tile (64n x 512c bf16) -> ks (XOR-swizzled per 8-chunk)
  //    elem (n, c) at ks[n*512 + ((c>>3 ^ (n&7))*8) + (c&7)]
#pragma unroll
  for (int rs = 0; rs < 4; rs++) {
#pragma unroll
    for (int ct = 0; ct < 4; ct++) {
      int c = w * 64 + ct * 16 + col;
      int chunk = c >> 3;
#pragma unroll
      for (int reg = 0; reg < 4; reg++) {
        int n = rs * 16 + quad * 4 + reg;
        ks[n * 512 + ((chunk ^ (n & 7)) * 8) + (c & 7)] =
            f2bf(acc[rs * 4 + ct][reg] * dred[n]);
      }
    }
  }
  __syncthreads();

  // 2) GEMM: out[b][d][n0+n] = relu(sum_c wT[d][c]*tile[n][c]); wave owns 64 d
  //    wT loads ping-ponged one kc ahead (afA/afB); acc freed -> acc2.
  {
    f4v acc2[16];
#pragma unroll
    for (int i = 0; i < 16; i++) acc2[i] = (f4v){0.f, 0.f, 0.f, 0.f};
#pragma unroll 1
    for (int kc = 0; kc < 16; kc += 2) {
      // prefetch kc+1
#pragma unroll
      for (int rs = 0; rs < 4; rs++)
        afB[rs] = *(const s8v*)(ab + (size_t)(rs * 16) * 512 + (kc + 1) * 32);
      {
        s8v bf[4];
#pragma unroll
        for (int ct = 0; ct < 4; ct++) {
          int n = ct * 16 + col;  // n&7 == cs
          bf[ct] = *(const s8v*)(ks + n * 512 + (((kc * 4 + quad) ^ cs) * 8));
        }
        __builtin_amdgcn_s_setprio(1);
#pragma unroll
        for (int rs = 0; rs < 4; rs++)
#pragma unroll
          for (int ct = 0; ct < 4; ct++)
            acc2[rs * 4 + ct] = __builtin_amdgcn_mfma_f32_16x16x32_bf16(
                afA[rs], bf[ct], acc2[rs * 4 + ct], 0, 0, 0);
        __builtin_amdgcn_s_setprio(0);
      }
      // prefetch kc+2
      if (kc + 2 < 16) {
#pragma unroll
        for (int rs = 0; rs < 4; rs++)
          afA[rs] = *(const s8v*)(ab + (size_t)(rs * 16) * 512 + (kc + 2) * 32);
      }
      {
        s8v bf[4];
#pragma unroll
        for (int ct = 0; ct < 4; ct++) {
          int n = ct * 16 + col;
          bf[ct] = *(const s8v*)(ks + n * 512 + ((((kc + 1) * 4 + quad) ^ cs) * 8));
        }
        __builtin_amdgcn_s_setprio(1);
#pragma unroll
        for (int rs = 0; rs < 4; rs++)
#pragma unroll
          for (int ct = 0; ct < 4; ct++)
            acc2[rs * 4 + ct] = __builtin_amdgcn_mfma_f32_16x16x32_bf16(
                afB[rs], bf[ct], acc2[rs * 4 + ct], 0, 0, 0);
        __builtin_amdgcn_s_setprio(0);
      }
    }
#pragma unroll
    for (int rs = 0; rs < 4; rs++) {
#pragma unroll
      for (int ct = 0; ct < 4; ct++) {
#pragma unroll
        for (int reg = 0; reg < 4; reg++) {
          int d = w * 64 + rs * 16 + quad * 4 + reg;
          int n = n0 + ct * 16 + col;
          out[((size_t)(b * 512 + d)) * 4096 + n] = fmaxf(acc2[rs * 4 + ct][reg], 0.f);
        }
      }
    }
  }
}

extern "C" void kernel_launch(void* const* d_in, const int* in_sizes, int n_in,
                              void* d_out, int out_size, void* d_ws, size_t ws_size,
                              hipStream_t stream) {
  const float* feat    = (const float*)d_in[0];
  const float* phi_w   = (const float*)d_in[1];
  const float* theta_w = (const float*)d_in[2];
  const float* weight  = (const float*)d_in[3];
  float* out = (float*)d_out;

  ushort* wsu = (ushort*)d_ws;
  ushort* featT   = wsu;
  ushort* featV   = wsu + 16777216;
  ushort* phi_n   = wsu + 33554432;
  ushort* theta_n = wsu + 41943040;
  ushort* wbp     = wsu + 50331648;
  ushort* wbt     = wsu + 50462720;
  ushort* weightT = wsu + 50593792;

  k0<<<dim3(4416), dim3(256), 0, stream>>>(feat, phi_w, theta_w, weight,
                                           featT, featV, wbp, wbt, weightT);
  k1_gemm<<<dim3(512), dim3(512), 0, stream>>>(featT, wbp, wbt, phi_n, theta_n);
  k3_attn<<<dim3(512), dim3(512), 0, stream>>>(phi_n, theta_n, featV, weightT, out);
}